// Round 18
// baseline (615.708 us; speedup 1.0000x reference)
//
#include <hip/hip_runtime.h>

// ---------------------------------------------------------------------------
// Decoder layer (B=4, S=2048, D=1024, H=16, Dh=64, FF=4096), f32 in/out.
// Round 18: gemm9 — 256x256 tile, BK=32, FOUR LDS buffers (128KB), prefetch
// depth 3 tiles, counted vmcnt(8) (vmcnt(4)/(0) only in epilogue), ONE
// barrier per tile (per 32 MFMA). Covers HBM-miss latency (~900cyc) that the
// r13 2-tile scheme couldn't. Same swizzles/epilogues as before.
// Flash v8 (128-kv chunks) / gemm3 / ln / cvt / transw unchanged from r17.
// ---------------------------------------------------------------------------

typedef _Float16 f16;
typedef _Float16 f16x8 __attribute__((ext_vector_type(8)));
typedef _Float16 f16x4 __attribute__((ext_vector_type(4)));
typedef __fp16 fp16x2 __attribute__((ext_vector_type(2)));
typedef float f32x4 __attribute__((ext_vector_type(4)));
typedef float f32x16 __attribute__((ext_vector_type(16)));
typedef unsigned int u32;

#define AS1 __attribute__((address_space(1)))
#define AS3 __attribute__((address_space(3)))

constexpr int S_LEN = 2048;
constexpr int DM    = 1024;

// ---- static device arena (byte offsets) ----
constexpr long OFF_W    = 0;
constexpr long OFF_XB   = 32L  << 20;
constexpr long OFF_ENC  = 48L  << 20;
constexpr long OFF_Q    = 64L  << 20;
constexpr long OFF_K    = 80L  << 20;
constexpr long OFF_V    = 96L  << 20;
constexpr long OFF_VT   = 112L << 20;
constexpr long OFF_AC   = 128L << 20;
constexpr long OFF_HID  = 144L << 20;
constexpr long OFF_F2   = 240L << 20;
constexpr long OFF_PART = 304L << 20;
constexpr long BUF_BYTES = 336L << 20;

__device__ alignas(4096) unsigned char g_buf[BUF_BYTES];

constexpr long WQ1T = OFF_W + (0L  << 20);
constexpr long WF1T = OFF_W + (16L << 20);  // [4096][1024]
constexpr long WF2T = OFF_W + (24L << 20);  // [1024][4096]
constexpr long WO1T = OFF_W + (6L  << 20);
constexpr long WQ2T = OFF_W + (8L  << 20);
constexpr long WV2T = OFF_W + (12L << 20);
constexpr long WO2T = OFF_W + (14L << 20);

// ---------------------------------------------------------------------------
__global__ __launch_bounds__(256) void cvt2_k(const float* __restrict__ x,
                                              const float* __restrict__ enc)
{
    const int bid = blockIdx.x;
    const bool second = bid >= 8192;
    const float* in = second ? enc : x;
    f16* out = (f16*)(g_buf + (second ? OFF_ENC : OFF_XB));
    long i = (long)(second ? bid - 8192 : bid) * 256 + threadIdx.x;
    float4 v = ((const float4*)in)[i];
    f16x4 h;
    h[0] = (f16)v.x; h[1] = (f16)v.y; h[2] = (f16)v.z; h[3] = (f16)v.w;
    *(f16x4*)(out + i * 4) = h;
}

// ---------------------------------------------------------------------------
struct TWJobs { const float* src[10]; };

__global__ __launch_bounds__(256) void transw_all_k(TWJobs jobs)
{
    __shared__ float t[32][33];
    const int bid = blockIdx.x;
    int j, local;
    if (bid < 8192)       { j = bid >> 10; local = bid & 1023; }
    else if (bid < 12288) { j = 8; local = bid - 8192; }
    else                  { j = 9; local = bid - 12288; }
    const int K = (j == 9) ? 4096 : 1024;
    const int N = (j == 8) ? 4096 : 1024;
    const int tnx = N >> 5;
    const int tx32 = local % tnx, ty32 = local / tnx;
    const long dstOff = (j < 8) ? (long)j * (2L << 20) : ((j == 8) ? WF1T : WF2T);
    const float* W = jobs.src[j];
    f16* Wt = (f16*)(g_buf + dstOff);

    int tx = threadIdx.x, ty = threadIdx.y;
    int c0 = tx32 * 32, r0 = ty32 * 32;
#pragma unroll
    for (int i = 0; i < 4; ++i)
        t[ty + 8*i][tx] = W[(long)(r0 + ty + 8*i) * N + c0 + tx];
    __syncthreads();
#pragma unroll
    for (int i = 0; i < 4; ++i)
        Wt[(long)(c0 + ty + 8*i) * K + r0 + tx] = (f16)t[tx][ty + 8*i];
}

// ---------------------------------------------------------------------------
// GEMM v3 (unchanged): 128x128, BK=32, 4 waves, triple-buffered, counted
// vmcnt. Used for AO1/AO2/V2.
// ---------------------------------------------------------------------------
template<int MODE>
__global__ __launch_bounds__(256) void gemm3_k(
    long aOff, long bOff, long cOff, long vtOff,
    const float* __restrict__ b0, const float* __restrict__ b1,
    const float* __restrict__ b2, const float* __restrict__ b3,
    int K, int lda, int ldb, int ldc, long chunkStride, int tvch)
{
    __shared__ alignas(16) f16 As[3][128 * 32];
    __shared__ alignas(16) f16 Bs[3][128 * 32];

    const int tid  = threadIdx.x;
    const int lane = tid & 63;
    const int w    = tid >> 6;
    const int cB   = lane & 15;
    const int hi   = lane >> 4;

    const int nwg = gridDim.x * gridDim.y;
    const int id  = blockIdx.y * gridDim.x + blockIdx.x;
    const int swz = (id & 7) * (nwg >> 3) + (id >> 3);
    const int bx  = swz % gridDim.x, by = swz / gridDim.x;
    const int row0 = by * 128, col0 = bx * 128;

    const f16* Ab = (const f16*)(g_buf + aOff);
    const f16* Bb = (const f16*)(g_buf + bOff);

    const int wr = (w >> 1) * 64;
    const int wc = (w & 1) * 64;

    f32x4 acc[4][4] = {};

    auto stage = [&](int buf, int kt) {
        const int kB = kt * 32;
        const int base = w * 64;
#pragma unroll
        for (int r = 0; r < 2; ++r) {
            const int idx  = r * 256 + base + lane;
            const int srow = idx >> 2, sb = idx & 3;
            const int gk = (sb ^ ((srow >> 1) & 3)) << 3;
            __builtin_amdgcn_global_load_lds(
                (const AS1 void*)(Ab + (long)(row0 + srow) * lda + kB + gk),
                (AS3 void*)(&As[buf][(r * 256 + base) * 8]), 16, 0, 0);
            __builtin_amdgcn_global_load_lds(
                (const AS1 void*)(Bb + (long)(col0 + srow) * ldb + kB + gk),
                (AS3 void*)(&Bs[buf][(r * 256 + base) * 8]), 16, 0, 0);
        }
    };

    const int nt = K >> 5;
    stage(0, 0);
    stage(1, 1);

    for (int t = 0; t < nt; ++t) {
        if (nt - t >= 2) asm volatile("s_waitcnt vmcnt(4)" ::: "memory");
        else             asm volatile("s_waitcnt vmcnt(0)" ::: "memory");
        __builtin_amdgcn_s_barrier();
        __builtin_amdgcn_sched_barrier(0);
        if (t + 2 < nt) stage((t + 2) % 3, t + 2);

        const int cur = t % 3;
        f16x8 af[4], bf[4];
#pragma unroll
        for (int m = 0; m < 4; ++m) {
            const int row = wr + m * 16 + cB;
            af[m] = *(const f16x8*)&As[cur][row * 32 + ((hi ^ ((row >> 1) & 3)) << 3)];
        }
#pragma unroll
        for (int n = 0; n < 4; ++n) {
            const int row = wc + n * 16 + cB;
            bf[n] = *(const f16x8*)&Bs[cur][row * 32 + ((hi ^ ((row >> 1) & 3)) << 3)];
        }
        __builtin_amdgcn_s_setprio(1);
#pragma unroll
        for (int m = 0; m < 4; ++m)
#pragma unroll
            for (int n = 0; n < 4; ++n)
                acc[m][n] = __builtin_amdgcn_mfma_f32_16x16x32_f16(af[m], bf[n], acc[m][n], 0, 0, 0);
        __builtin_amdgcn_s_setprio(0);
    }

    const int ch = col0 >> 10;
    const float* bp = (ch == 0) ? b0 : (ch == 1) ? b1 : (ch == 2) ? b2 : b3;

    if (MODE == 0 && ch == tvch) {
        f16* Vt = (f16*)(g_buf + vtOff);
#pragma unroll
        for (int m = 0; m < 4; ++m) {
#pragma unroll
            for (int n = 0; n < 4; ++n) {
                const int c = col0 + wc + n * 16 + cB;
                const int hh = (c >> 6) & 15, dd = c & 63;
                const float bv = bp[c & 1023];
                const int r0e = row0 + wr + m * 16 + hi * 4;
                const int bb = r0e >> 11, sS = r0e & 2047;
                f16x4 hv;
#pragma unroll
                for (int jj = 0; jj < 4; ++jj) hv[jj] = (f16)(acc[m][n][jj] + bv);
                *(f16x4*)(Vt + (((long)(bb * 16 + hh) * 64 + dd) * 2048 + sS)) = hv;
            }
        }
        return;
    }

    float* Cf = (float*)(g_buf + cOff);
    f16*  Ch = (f16*)(g_buf + cOff);
    const long cBase = (long)ch * chunkStride;
#pragma unroll
    for (int m = 0; m < 4; ++m) {
#pragma unroll
        for (int n = 0; n < 4; ++n) {
            const int c = col0 + wc + n * 16 + cB;
            const float bv = bp[c & 1023];
#pragma unroll
            for (int jj = 0; jj < 4; ++jj) {
                const int r = row0 + wr + m * 16 + hi * 4 + jj;
                float v = acc[m][n][jj] + bv;
                const long idx = cBase + (long)r * ldc + (c & 1023);
                if constexpr (MODE == 2) Cf[idx] = v;
                else                     Ch[idx] = (f16)v;
            }
        }
    }
}

// ---------------------------------------------------------------------------
// GEMM v9: 256x256 tile, BK=32, 8 waves (2Mx4N, wave tile 128x64).
// FOUR LDS buffers (A 4x16KB + B 4x16KB = 128KB), prefetch depth 3 tiles,
// vmcnt(8) steady state (4/0 in epilogue), ONE barrier per tile.
// Per tile: {vmcnt -> bar -> [read B+A-lo | stage(t+3)] -> lgkm -> 16 MFMA
//            -> read A-hi -> lgkm -> 16 MFMA}.
// Same XOR swizzle / XCD swizzle / chunked epilogue / fused V-transpose /
// split-K as gemm8. MODE 0: f16+bias (+Vt chunk tvch), 1: +relu, 2: f32.
// ---------------------------------------------------------------------------
template<int MODE>
__global__ __launch_bounds__(512, 1) void gemm9_k(
    long aOff, long bOff, long cOff, long partOff, long vtOff,
    const float* __restrict__ b0, const float* __restrict__ b1,
    const float* __restrict__ b2, const float* __restrict__ b3,
    int K, int lda, int ldb, int ldc, long chunkStride, int tvch)
{
    __shared__ alignas(16) f16 As[4][8192];   // [buf][256*32]
    __shared__ alignas(16) f16 Bs[4][8192];

    const int tid  = threadIdx.x;
    const int lane = tid & 63;
    const int w    = tid >> 6;
    const int cB   = lane & 15;
    const int hi   = lane >> 4;

    const int gx = gridDim.x, gy = gridDim.y;
    const int nwg = gx * gy * gridDim.z;
    const int id  = ((int)blockIdx.z * gy + (int)blockIdx.y) * gx + (int)blockIdx.x;
    const int swz = (id & 7) * (nwg >> 3) + (id >> 3);
    const int bx  = swz % gx;
    const int rem = swz / gx;
    const int by  = rem % gy;
    const int bz  = rem / gy;
    const int row0 = by * 256, col0 = bx * 256;

    const f16* Ab = (const f16*)(g_buf + aOff) + (long)bz * K;
    const f16* Bb = (const f16*)(g_buf + bOff) + (long)bz * K;

    const int wr = (w >> 2) * 128;
    const int wc = (w & 3) * 64;

    f32x4 acc[8][4] = {};

    // stage one full BK=32 tile (A 16KB + B 16KB), 4 issues/thread
    auto stageTile = [&](int buf, int kt) {
        const int kB = kt * 32;
#pragma unroll
        for (int r = 0; r < 2; ++r) {
            const int idx  = r * 512 + w * 64 + lane;      // 0..1023
            const int srow = idx >> 2, sb = idx & 3;
            const int gk = (sb ^ ((srow >> 1) & 3)) << 3;
            __builtin_amdgcn_global_load_lds(
                (const AS1 void*)(Ab + (long)(row0 + srow) * lda + kB + gk),
                (AS3 void*)(&As[buf][(r * 512 + w * 64) * 8]), 16, 0, 0);
        }
#pragma unroll
        for (int r = 0; r < 2; ++r) {
            const int idx  = r * 512 + w * 64 + lane;
            const int srow = idx >> 2, sb = idx & 3;
            const int gk = (sb ^ ((srow >> 1) & 3)) << 3;
            __builtin_amdgcn_global_load_lds(
                (const AS1 void*)(Bb + (long)(col0 + srow) * ldb + kB + gk),
                (AS3 void*)(&Bs[buf][(r * 512 + w * 64) * 8]), 16, 0, 0);
        }
    };

    auto rdA = [&](int buf, int mf) -> f16x8 {
        const int row = wr + mf * 16 + cB;
        return *(const f16x8*)&As[buf][row * 32 + ((hi ^ ((row >> 1) & 3)) << 3)];
    };
    auto rdB = [&](int buf, int nf) -> f16x8 {
        const int row = wc + nf * 16 + cB;
        return *(const f16x8*)&Bs[buf][row * 32 + ((hi ^ ((row >> 1) & 3)) << 3)];
    };

    const int nt = K >> 5;
    stageTile(0, 0);
    stageTile(1, 1);
    stageTile(2, 2);          // 12 issues outstanding per thread

    for (int t = 0; t < nt; ++t) {
        const int cur = t & 3;
        // entry wait: tile t landed; up to 2 newer tiles stay in flight
        if (t <= nt - 3)      asm volatile("s_waitcnt vmcnt(8)" ::: "memory");
        else if (t == nt - 2) asm volatile("s_waitcnt vmcnt(4)" ::: "memory");
        else                  asm volatile("s_waitcnt vmcnt(0)" ::: "memory");
        __builtin_amdgcn_s_barrier();
        __builtin_amdgcn_sched_barrier(0);

        f16x8 a[4], b[4];
#pragma unroll
        for (int n = 0; n < 4; ++n) b[n] = rdB(cur, n);
#pragma unroll
        for (int m = 0; m < 4; ++m) a[m] = rdA(cur, m);
        if (t + 3 < nt) stageTile((t + 3) & 3, t + 3);
        asm volatile("s_waitcnt lgkmcnt(0)" ::: "memory");
        __builtin_amdgcn_sched_barrier(0);
        __builtin_amdgcn_s_setprio(1);
#pragma unroll
        for (int m = 0; m < 4; ++m)
#pragma unroll
            for (int n = 0; n < 4; ++n)
                acc[m][n] = __builtin_amdgcn_mfma_f32_16x16x32_f16(a[m], b[n], acc[m][n], 0, 0, 0);
        __builtin_amdgcn_s_setprio(0);
        __builtin_amdgcn_sched_barrier(0);

#pragma unroll
        for (int m = 0; m < 4; ++m) a[m] = rdA(cur, m + 4);
        asm volatile("s_waitcnt lgkmcnt(0)" ::: "memory");
        __builtin_amdgcn_sched_barrier(0);
        __builtin_amdgcn_s_setprio(1);
#pragma unroll
        for (int m = 0; m < 4; ++m)
#pragma unroll
            for (int n = 0; n < 4; ++n)
                acc[4 + m][n] = __builtin_amdgcn_mfma_f32_16x16x32_f16(a[m], b[n], acc[4 + m][n], 0, 0, 0);
        __builtin_amdgcn_s_setprio(0);
    }

    const int ch = col0 >> 10;
    const float* bp = (ch == 0) ? b0 : (ch == 1) ? b1 : (ch == 2) ? b2 : b3;

    if (MODE == 0 && ch == tvch) {
        f16* Vt = (f16*)(g_buf + vtOff);
#pragma unroll
        for (int m = 0; m < 8; ++m) {
#pragma unroll
            for (int n = 0; n < 4; ++n) {
                const int c = col0 + wc + n * 16 + cB;
                const int hh = (c >> 6) & 15, dd = c & 63;
                const float bv = bp[c & 1023];
                const int r0e = row0 + wr + m * 16 + hi * 4;
                const int bb = r0e >> 11, sS = r0e & 2047;
                f16x4 hv;
#pragma unroll
                for (int jj = 0; jj < 4; ++jj) hv[jj] = (f16)(acc[m][n][jj] + bv);
                *(f16x4*)(Vt + (((long)(bb * 16 + hh) * 64 + dd) * 2048 + sS)) = hv;
            }
        }
        return;
    }

    float* Cf = (float*)(g_buf + (bz ? partOff : cOff));
    f16*  Ch = (f16*)(g_buf + cOff);
    const long cBase = (long)ch * chunkStride;
#pragma unroll
    for (int m = 0; m < 8; ++m) {
#pragma unroll
        for (int n = 0; n < 4; ++n) {
            const int c = col0 + wc + n * 16 + cB;
            const float bv = bz ? 0.f : bp[c & 1023];
#pragma unroll
            for (int jj = 0; jj < 4; ++jj) {
                const int r = row0 + wr + m * 16 + hi * 4 + jj;
                float v = acc[m][n][jj] + bv;
                if constexpr (MODE == 1) v = fmaxf(v, 0.f);
                const long idx = cBase + (long)r * ldc + (c & 1023);
                if constexpr (MODE == 2) Cf[idx] = v;
                else                     Ch[idx] = (f16)v;
            }
        }
    }
}

// ---------------------------------------------------------------------------
// Fused flash attention v8 (unchanged from r17): 128 kv per barrier, two
// 64-kv sub-iterations; K LDS [128][64], V LDS [64][128]; LDS 64KB.
// ---------------------------------------------------------------------------
template<int CAUSAL>
__global__ __launch_bounds__(512, 2) void flash_k(long qOff, long kOff, long vtOff, long oOff)
{
    __shared__ alignas(16) f16 SH[32768];   // [buf 16384 f16: K 8192 | V 8192]

    const int tid  = threadIdx.x;
    const int lane = tid & 63;
    const int w    = tid >> 6;
    const int ql   = lane & 31;
    const int s    = lane >> 5;

    const int raw   = (int)blockIdx.y * (int)gridDim.x + (int)blockIdx.x;  // 512
    const int newid = (raw & 7) * 64 + (raw >> 3);
    const int bh    = newid >> 3;
    const int p     = newid & 7;

    const int qt  = CAUSAL ? ((w >> 2) ? 15 - p : p) : (2 * p + (w >> 2));
    const int q0w = qt * 128 + (w & 3) * 32;
    const int nch = CAUSAL ? (16 - p) : 16;     // chunks of 128 kv

    const int b = bh >> 4, h = bh & 15;
    const long tokB = (long)b * S_LEN;

    const f16* Qb  = (const f16*)(g_buf + qOff);
    const f16* Kb  = (const f16*)(g_buf + kOff);
    const f16* Vtb = (const f16*)(g_buf + vtOff) + (long)bh * 64 * S_LEN;
    f16* Ob = (f16*)(g_buf + oOff);

    const int r8  = lane >> 3;
    const int c8  = lane & 7;
    const int sbK = c8 ^ r8;
    const int d16 = lane >> 4;
    const int b16 = lane & 15;

    auto stage = [&](int buf, int c) {
        const int kv0s = c * 128;
#pragma unroll
        for (int r = 0; r < 2; ++r) {
            const int row = w * 16 + r * 8 + r8;
            __builtin_amdgcn_global_load_lds(
                (const AS1 void*)(Kb + (tokB + kv0s + row) * DM + h * 64 + sbK * 8),
                (AS3 void*)(&SH[buf * 16384 + (w * 16 + r * 8) * 64]), 16, 0, 0);
        }
#pragma unroll
        for (int r = 0; r < 2; ++r) {
            const int d = w * 8 + r * 4 + d16;
            __builtin_amdgcn_global_load_lds(
                (const AS1 void*)(Vtb + (long)d * S_LEN + kv0s + (b16 ^ (d & 7)) * 8),
                (AS3 void*)(&SH[buf * 16384 + 8192 + (w * 8 + r * 4) * 128]), 16, 0, 0);
        }
    };

    stage(0, 0);

    f16x8 qf[4];
    {
        const f16 hs = (f16)(0.125f * 1.44269504088896f);
        const f16* qrow = Qb + (tokB + q0w + ql) * DM + h * 64 + s * 8;
#pragma unroll
        for (int kk = 0; kk < 4; ++kk) {
            qf[kk] = *(const f16x8*)(qrow + kk * 16);
#pragma unroll
            for (int i = 0; i < 8; ++i) qf[kk][i] = qf[kk][i] * hs;
        }
    }

    f32x16 oacc[2] = {};
    float lrow = 0.f;

    for (int c = 0; c < nch; ++c) {
        const int cur = c & 1;

        asm volatile("s_waitcnt vmcnt(0) lgkmcnt(0)" ::: "memory");
        __builtin_amdgcn_sched_barrier(0);
        __builtin_amdgcn_s_barrier();
        __builtin_amdgcn_sched_barrier(0);
        if (c + 1 < nch) stage(cur ^ 1, c + 1);

        const char* Kl = (const char*)SH + cur * 32768;
        const char* Vl = Kl + 16384;

#pragma unroll
        for (int sub = 0; sub < 2; ++sub) {
            const int kv0 = c * 128 + sub * 64;
            const bool active = !CAUSAL || (kv0 <= q0w + 31);
            if (!active) continue;

            f32x16 pr[2] = {};
            __builtin_amdgcn_s_setprio(1);
#pragma unroll
            for (int kk = 0; kk < 4; ++kk) {
                const int t16 = (kk * 2 + s) ^ (ql & 7);
                f16x8 kf0 = *(const f16x8*)(Kl + (sub * 64 + ql) * 128 + t16 * 16);
                f16x8 kf1 = *(const f16x8*)(Kl + (sub * 64 + 32 + ql) * 128 + t16 * 16);
                pr[0] = __builtin_amdgcn_mfma_f32_32x32x16_f16(kf0, qf[kk], pr[0], 0, 0, 0);
                pr[1] = __builtin_amdgcn_mfma_f32_32x32x16_f16(kf1, qf[kk], pr[1], 0, 0, 0);
            }
            __builtin_amdgcn_s_setprio(0);

            if (CAUSAL && (kv0 + 63 > q0w)) {
                const int q = q0w + ql;
#pragma unroll
                for (int v = 0; v < 2; ++v)
#pragma unroll
                    for (int r = 0; r < 16; ++r) {
                        const int kv = kv0 + v * 32 + (r & 3) + 8 * (r >> 2) + 4 * s;
                        if (kv > q) pr[v][r] = -1e30f;
                    }
            }

            u32 pk[2][4][2];
            float rp[4] = {0.f, 0.f, 0.f, 0.f};
#pragma unroll
            for (int v = 0; v < 2; ++v)
#pragma unroll
                for (int a = 0; a < 4; ++a)
#pragma unroll
                    for (int cc = 0; cc < 2; ++cc) {
                        const float e0 = __builtin_amdgcn_exp2f(pr[v][4 * a + 2 * cc] - 8.0f);
                        const float e1 = __builtin_amdgcn_exp2f(pr[v][4 * a + 2 * cc + 1] - 8.0f);
                        rp[a] += e0 + e1;
                        union { fp16x2 h; u32 u; } cv;
                        cv.h = __builtin_amdgcn_cvt_pkrtz(e0, e1);
                        pk[v][a][cc] = cv.u;
                    }
            float rsum = (rp[0] + rp[1]) + (rp[2] + rp[3]);
            rsum += __shfl_xor(rsum, 32);
            lrow += rsum;

            u32 loc[2][2][2], exv[2][2][2];
#pragma unroll
            for (int v = 0; v < 2; ++v)
#pragma unroll
                for (int k1 = 0; k1 < 2; ++k1)
#pragma unroll
                    for (int cc = 0; cc < 2; ++cc) {
                        const u32 pe = pk[v][2 * k1][cc];
                        const u32 po = pk[v][2 * k1 + 1][cc];
                        loc[v][k1][cc] = s ? po : pe;
                        const u32 snd = s ? pe : po;
                        exv[v][k1][cc] = (u32)__shfl_xor((int)snd, 32);
                    }

            __builtin_amdgcn_s_setprio(1);
#pragma unroll
            for (int ks = 0; ks < 4; ++ks) {
                const int v = ks >> 1, k1 = ks & 1;
                union { u32 u[4]; f16x8 hv; } pa;
                pa.u[0] = s ? exv[v][k1][0] : loc[v][k1][0];
                pa.u[1] = s ? exv[v][k1][1] : loc[v][k1][1];
                pa.u[2] = s ? loc[v][k1][0] : exv[v][k1][0];
                pa.u[3] = s ? loc[v][k1][1] : exv[v][k1][1];
                const int tv = sub * 8 + ((ks * 2 + s) ^ (ql & 7));
                f16x8 vf0 = *(const f16x8*)(Vl + ql * 256 + tv * 16);
                f16x8 vf1 = *(const f16x8*)(Vl + (32 + ql) * 256 + tv * 16);
                oacc[0] = __builtin_amdgcn_mfma_f32_32x32x16_f16(pa.hv, vf0, oacc[0], 0, 0, 0);
                oacc[1] = __builtin_amdgcn_mfma_f32_32x32x16_f16(pa.hv, vf1, oacc[1], 0, 0, 0);
            }
            __builtin_amdgcn_s_setprio(0);
        }
    }

    asm volatile("s_waitcnt lgkmcnt(0)" ::: "memory");
    __builtin_amdgcn_sched_barrier(0);
    __builtin_amdgcn_s_barrier();

    f16* Es = SH + w * 2304;
    const float linv = 1.0f / lrow;
#pragma unroll
    for (int r = 0; r < 16; ++r) {
        const int qr = (r & 3) + 8 * (r >> 2) + 4 * s;
        const float lb = __shfl(linv, qr);
        Es[qr * 72 + ql]      = (f16)(oacc[0][r] * lb);
        Es[qr * 72 + 32 + ql] = (f16)(oacc[1][r] * lb);
    }
    const int orow = lane >> 1;
    const int oh   = (lane & 1) * 32;
    const f16* srcp = Es + orow * 72 + oh;
    f16* dst = Ob + (tokB + q0w + orow) * DM + h * 64 + oh;
#pragma unroll
    for (int t = 0; t < 4; ++t)
        *(f16x8*)(dst + t * 8) = *(const f16x8*)(srcp + t * 8);
}

// ---------------------------------------------------------------------------
// fused residual-add + LayerNorm (r15 form).
// ---------------------------------------------------------------------------
__global__ __launch_bounds__(256) void ln_k(
    long inOff, long in2Off, const float* __restrict__ residF, long residHOff,
    const float* __restrict__ gamma, const float* __restrict__ beta,
    float* __restrict__ outFExt, long outHOff)
{
    const float* in = (const float*)(g_buf + inOff);

    const long row = blockIdx.x;
    const int tid = threadIdx.x;
    const int lane = tid & 63, wid = tid >> 6;

    float4 a = ((const float4*)(in + row * DM))[tid];
    float x0 = a.x, x1 = a.y, x2 = a.z, x3 = a.w;
    if (residF) {
        float4 rr = ((const float4*)(residF + row * DM))[tid];
        x0 += rr.x; x1 += rr.y; x2 += rr.z; x3 += rr.w;
    }
    if (residHOff >= 0) {
        const f16* rh = (const f16*)(g_buf + residHOff) + row * DM + tid * 4;
        f16x4 rv = *(const f16x4*)rh;
        x0 += (float)rv[0]; x1 += (float)rv[1]; x2 += (float)rv[2]; x3 += (float)rv[3];
    }
    if (in2Off >= 0) {
        const float* in2 = (const float*)(g_buf + in2Off);
        float4 p = ((const float4*)(in2 + row * DM))[tid];
        x0 += p.x; x1 += p.y; x2 += p.z; x3 += p.w;
    }

    __shared__ float red[4];
    float ss = x0 + x1 + x2 + x3;
#pragma unroll
    for (int o = 32; o > 0; o >>= 1) ss += __shfl_xor(ss, o);
    if (lane == 0) red[wid] = ss;
    __syncthreads();
    const float mu = (red[0] + red[1] + red[2] + red[3]) * (1.0f / DM);

    float d0 = x0 - mu, d1 = x1 - mu, d2 = x2 - mu, d3 = x3 - mu;
    float qq = d0*d0 + d1*d1 + d2*d2 + d3*d3;
#pragma unroll
    for (int o = 32; o > 0; o >>= 1) qq += __shfl_xor(qq, o);
    __syncthreads();
    if (lane == 0) red[wid] = qq;
    __syncthreads();
    const float var = (red[0] + red[1] + red[2] + red[3]) * (1.0f / DM);
    const float rs = rsqrtf(var + 1e-6f);

    float4 g  = ((const float4*)gamma)[tid];
    float4 be = ((const float4*)beta)[tid];
    float y0 = d0 * rs * g.x + be.x;
    float y1 = d1 * rs * g.y + be.y;
    float y2 = d2 * rs * g.z + be.z;
    float y3 = d3 * rs * g.w + be.w;

    if (outFExt)
        ((float4*)(outFExt + row * DM))[tid] = make_float4(y0, y1, y2, y3);
    if (outHOff >= 0) {
        f16* outH = (f16*)(g_buf + outHOff);
        f16x4 hh; hh[0] = (f16)y0; hh[1] = (f16)y1; hh[2] = (f16)y2; hh[3] = (f16)y3;
        *(f16x4*)(outH + row * DM + tid * 4) = hh;
    }
}

// ---------------------------------------------------------------------------
extern "C" void kernel_launch(void* const* d_in, const int* in_sizes, int n_in,
                              void* d_out, int out_size, void* d_ws, size_t ws_size,
                              hipStream_t stream)
{
    (void)in_sizes; (void)n_in; (void)d_ws; (void)ws_size; (void)out_size;
    const float* x   = (const float*)d_in[0];
    const float* enc = (const float*)d_in[1];
    const float* wq1 = (const float*)d_in[2];  const float* bq1 = (const float*)d_in[3];
    const float* wk1 = (const float*)d_in[4];  const float* bk1 = (const float*)d_in[5];
    const float* wv1 = (const float*)d_in[6];  const float* bv1 = (const float*)d_in[7];
    const float* wo1 = (const float*)d_in[8];  const float* bo1 = (const float*)d_in[9];
    const float* wq2 = (const float*)d_in[10]; const float* bq2 = (const float*)d_in[11];
    const float* wk2 = (const float*)d_in[12]; const float* bk2 = (const float*)d_in[13];
    const float* wv2 = (const float*)d_in[14]; const float* bv2 = (const float*)d_in[15];
    const float* wo2 = (const float*)d_in[16]; const float* bo2 = (const float*)d_in[17];
    const float* wf1 = (const float*)d_in[18]; const float* bf1 = (const float*)d_in[19];
    const float* wf2 = (const float*)d_in[20]; const float* bf2 = (const float*)d_in[21];
    const float* g1  = (const float*)d_in[22]; const float* be1 = (const float*)d_in[23];
    const float* g2  = (const float*)d_in[24]; const float* be2 = (const float*)d_in[25];
    const float* g3  = (const float*)d_in[26]; const float* be3 = (const float*)d_in[27];
    float* out = (float*)d_out;

    const dim3 T256(256), T512(512), T32x8(32, 8);
    const long QKV_CHUNK = 8192L * 1024;

    // ---- converts + weight transposes ----
    cvt2_k<<<16384, T256, 0, stream>>>(x, enc);
    TWJobs jobs;
    jobs.src[0] = wq1; jobs.src[1] = wk1; jobs.src[2] = wv1; jobs.src[3] = wo1;
    jobs.src[4] = wq2; jobs.src[5] = wk2; jobs.src[6] = wv2; jobs.src[7] = wo2;
    jobs.src[8] = wf1; jobs.src[9] = wf2;
    transw_all_k<<<16384, T32x8, 0, stream>>>(jobs);

    // ---- masked self-attention ----
    gemm9_k<0><<<dim3(12, 32, 1), T512, 0, stream>>>(OFF_XB, WQ1T, OFF_Q, 0, OFF_VT,
        bq1, bk1, bv1, bv1, 1024, 1024, 1024, 1024, QKV_CHUNK, 2);
    flash_k<1><<<dim3(8, 64), T512, 0, stream>>>(OFF_Q, OFF_K, OFF_VT, OFF_AC);
    gemm3_k<2><<<dim3(8, 64), T256, 0, stream>>>(OFF_AC, WO1T, OFF_F2, 0,
        bo1, bo1, bo1, bo1, 1024, 1024, 1024, 1024, 1024, -1);
    ln_k<<<8192, T256, 0, stream>>>(OFF_F2, -1, x, -1, g1, be1, nullptr, OFF_XB);

    // ---- cross-attention (q=enc, k=enc, v=x1) ----
    gemm9_k<0><<<dim3(8, 32, 1), T512, 0, stream>>>(OFF_ENC, WQ2T, OFF_Q, 0, 0,
        bq2, bk2, bk2, bk2, 1024, 1024, 1024, 1024, QKV_CHUNK, -1);
    gemm3_k<0><<<dim3(8, 64), T256, 0, stream>>>(OFF_XB, WV2T, OFF_V, OFF_VT,
        bv2, bv2, bv2, bv2, 1024, 1024, 1024, 1024, 1024, 0);
    flash_k<0><<<dim3(8, 64), T512, 0, stream>>>(OFF_Q, OFF_K, OFF_VT, OFF_AC);
    gemm3_k<2><<<dim3(8, 64), T256, 0, stream>>>(OFF_AC, WO2T, OFF_F2, 0,
        bo2, bo2, bo2, bo2, 1024, 1024, 1024, 1024, 1024, -1);
    ln_k<<<8192, T256, 0, stream>>>(OFF_F2, -1, nullptr, OFF_XB, g2, be2, nullptr, OFF_XB);

    // ---- feed-forward ----
    gemm9_k<1><<<dim3(16, 32, 1), T512, 0, stream>>>(OFF_XB, WF1T, OFF_HID, 0, 0,
        bf1, bf1 + 1024, bf1 + 2048, bf1 + 3072, 1024, 1024, 1024, 4096, 1024, -1);
    gemm9_k<2><<<dim3(4, 32, 2), T512, 0, stream>>>(OFF_HID, WF2T, OFF_F2, OFF_PART, 0,
        bf2, bf2, bf2, bf2, 2048, 4096, 4096, 1024, 1024, -1);
    ln_k<<<8192, T256, 0, stream>>>(OFF_F2, OFF_PART, nullptr, OFF_XB, g3, be3, out, -1);
}

// Round 19
// 569.452 us; speedup vs baseline: 1.0812x; 1.0812x over previous
//
#include <hip/hip_runtime.h>

// ---------------------------------------------------------------------------
// Decoder layer (B=4, S=2048, D=1024, H=16, Dh=64, FF=4096), f32 in/out.
// Round 19: revert gemm9 -> gemm8 (r17 best state); ONE change: f16
// inter-kernel hand-offs. AO1/AO2 write f16 (gemm3 MODE 0), FF2 writes f16
// (gemm8 MODE 0, split-K partial f16 no-bias, epilogue partOff fix), and
// ln_k reads main/in2 inputs as f16. ~128MB less traffic.
// Flash v8 / cvt / transw unchanged from r17.
// ---------------------------------------------------------------------------

typedef _Float16 f16;
typedef _Float16 f16x8 __attribute__((ext_vector_type(8)));
typedef _Float16 f16x4 __attribute__((ext_vector_type(4)));
typedef __fp16 fp16x2 __attribute__((ext_vector_type(2)));
typedef float f32x4 __attribute__((ext_vector_type(4)));
typedef float f32x16 __attribute__((ext_vector_type(16)));
typedef unsigned int u32;

#define AS1 __attribute__((address_space(1)))
#define AS3 __attribute__((address_space(3)))

constexpr int S_LEN = 2048;
constexpr int DM    = 1024;

// ---- static device arena (byte offsets) ----
constexpr long OFF_W    = 0;
constexpr long OFF_XB   = 32L  << 20;
constexpr long OFF_ENC  = 48L  << 20;
constexpr long OFF_Q    = 64L  << 20;
constexpr long OFF_K    = 80L  << 20;
constexpr long OFF_V    = 96L  << 20;
constexpr long OFF_VT   = 112L << 20;
constexpr long OFF_AC   = 128L << 20;
constexpr long OFF_HID  = 144L << 20;
constexpr long OFF_F2   = 240L << 20;      // f16 now
constexpr long OFF_PART = 304L << 20;      // f16 split-K partial
constexpr long BUF_BYTES = 336L << 20;

__device__ alignas(4096) unsigned char g_buf[BUF_BYTES];

constexpr long WQ1T = OFF_W + (0L  << 20);
constexpr long WF1T = OFF_W + (16L << 20);  // [4096][1024]
constexpr long WF2T = OFF_W + (24L << 20);  // [1024][4096]
constexpr long WO1T = OFF_W + (6L  << 20);
constexpr long WQ2T = OFF_W + (8L  << 20);
constexpr long WV2T = OFF_W + (12L << 20);
constexpr long WO2T = OFF_W + (14L << 20);

// ---------------------------------------------------------------------------
__global__ __launch_bounds__(256) void cvt2_k(const float* __restrict__ x,
                                              const float* __restrict__ enc)
{
    const int bid = blockIdx.x;
    const bool second = bid >= 8192;
    const float* in = second ? enc : x;
    f16* out = (f16*)(g_buf + (second ? OFF_ENC : OFF_XB));
    long i = (long)(second ? bid - 8192 : bid) * 256 + threadIdx.x;
    float4 v = ((const float4*)in)[i];
    f16x4 h;
    h[0] = (f16)v.x; h[1] = (f16)v.y; h[2] = (f16)v.z; h[3] = (f16)v.w;
    *(f16x4*)(out + i * 4) = h;
}

// ---------------------------------------------------------------------------
struct TWJobs { const float* src[10]; };

__global__ __launch_bounds__(256) void transw_all_k(TWJobs jobs)
{
    __shared__ float t[32][33];
    const int bid = blockIdx.x;
    int j, local;
    if (bid < 8192)       { j = bid >> 10; local = bid & 1023; }
    else if (bid < 12288) { j = 8; local = bid - 8192; }
    else                  { j = 9; local = bid - 12288; }
    const int K = (j == 9) ? 4096 : 1024;
    const int N = (j == 8) ? 4096 : 1024;
    const int tnx = N >> 5;
    const int tx32 = local % tnx, ty32 = local / tnx;
    const long dstOff = (j < 8) ? (long)j * (2L << 20) : ((j == 8) ? WF1T : WF2T);
    const float* W = jobs.src[j];
    f16* Wt = (f16*)(g_buf + dstOff);

    int tx = threadIdx.x, ty = threadIdx.y;
    int c0 = tx32 * 32, r0 = ty32 * 32;
#pragma unroll
    for (int i = 0; i < 4; ++i)
        t[ty + 8*i][tx] = W[(long)(r0 + ty + 8*i) * N + c0 + tx];
    __syncthreads();
#pragma unroll
    for (int i = 0; i < 4; ++i)
        Wt[(long)(c0 + ty + 8*i) * K + r0 + tx] = (f16)t[tx][ty + 8*i];
}

// ---------------------------------------------------------------------------
// GEMM v3: 128x128, BK=32, 4 waves, triple-buffered, counted vmcnt.
// Used for AO1/AO2 (MODE 0, f16 out) and V2 (MODE 0 + fused V-transpose).
// ---------------------------------------------------------------------------
template<int MODE>
__global__ __launch_bounds__(256) void gemm3_k(
    long aOff, long bOff, long cOff, long vtOff,
    const float* __restrict__ b0, const float* __restrict__ b1,
    const float* __restrict__ b2, const float* __restrict__ b3,
    int K, int lda, int ldb, int ldc, long chunkStride, int tvch)
{
    __shared__ alignas(16) f16 As[3][128 * 32];
    __shared__ alignas(16) f16 Bs[3][128 * 32];

    const int tid  = threadIdx.x;
    const int lane = tid & 63;
    const int w    = tid >> 6;
    const int cB   = lane & 15;
    const int hi   = lane >> 4;

    const int nwg = gridDim.x * gridDim.y;
    const int id  = blockIdx.y * gridDim.x + blockIdx.x;
    const int swz = (id & 7) * (nwg >> 3) + (id >> 3);
    const int bx  = swz % gridDim.x, by = swz / gridDim.x;
    const int row0 = by * 128, col0 = bx * 128;

    const f16* Ab = (const f16*)(g_buf + aOff);
    const f16* Bb = (const f16*)(g_buf + bOff);

    const int wr = (w >> 1) * 64;
    const int wc = (w & 1) * 64;

    f32x4 acc[4][4] = {};

    auto stage = [&](int buf, int kt) {
        const int kB = kt * 32;
        const int base = w * 64;
#pragma unroll
        for (int r = 0; r < 2; ++r) {
            const int idx  = r * 256 + base + lane;
            const int srow = idx >> 2, sb = idx & 3;
            const int gk = (sb ^ ((srow >> 1) & 3)) << 3;
            __builtin_amdgcn_global_load_lds(
                (const AS1 void*)(Ab + (long)(row0 + srow) * lda + kB + gk),
                (AS3 void*)(&As[buf][(r * 256 + base) * 8]), 16, 0, 0);
            __builtin_amdgcn_global_load_lds(
                (const AS1 void*)(Bb + (long)(col0 + srow) * ldb + kB + gk),
                (AS3 void*)(&Bs[buf][(r * 256 + base) * 8]), 16, 0, 0);
        }
    };

    const int nt = K >> 5;
    stage(0, 0);
    stage(1, 1);

    for (int t = 0; t < nt; ++t) {
        if (nt - t >= 2) asm volatile("s_waitcnt vmcnt(4)" ::: "memory");
        else             asm volatile("s_waitcnt vmcnt(0)" ::: "memory");
        __builtin_amdgcn_s_barrier();
        __builtin_amdgcn_sched_barrier(0);
        if (t + 2 < nt) stage((t + 2) % 3, t + 2);

        const int cur = t % 3;
        f16x8 af[4], bf[4];
#pragma unroll
        for (int m = 0; m < 4; ++m) {
            const int row = wr + m * 16 + cB;
            af[m] = *(const f16x8*)&As[cur][row * 32 + ((hi ^ ((row >> 1) & 3)) << 3)];
        }
#pragma unroll
        for (int n = 0; n < 4; ++n) {
            const int row = wc + n * 16 + cB;
            bf[n] = *(const f16x8*)&Bs[cur][row * 32 + ((hi ^ ((row >> 1) & 3)) << 3)];
        }
        __builtin_amdgcn_s_setprio(1);
#pragma unroll
        for (int m = 0; m < 4; ++m)
#pragma unroll
            for (int n = 0; n < 4; ++n)
                acc[m][n] = __builtin_amdgcn_mfma_f32_16x16x32_f16(af[m], bf[n], acc[m][n], 0, 0, 0);
        __builtin_amdgcn_s_setprio(0);
    }

    const int ch = col0 >> 10;
    const float* bp = (ch == 0) ? b0 : (ch == 1) ? b1 : (ch == 2) ? b2 : b3;

    if (MODE == 0 && ch == tvch) {
        f16* Vt = (f16*)(g_buf + vtOff);
#pragma unroll
        for (int m = 0; m < 4; ++m) {
#pragma unroll
            for (int n = 0; n < 4; ++n) {
                const int c = col0 + wc + n * 16 + cB;
                const int hh = (c >> 6) & 15, dd = c & 63;
                const float bv = bp[c & 1023];
                const int r0e = row0 + wr + m * 16 + hi * 4;
                const int bb = r0e >> 11, sS = r0e & 2047;
                f16x4 hv;
#pragma unroll
                for (int jj = 0; jj < 4; ++jj) hv[jj] = (f16)(acc[m][n][jj] + bv);
                *(f16x4*)(Vt + (((long)(bb * 16 + hh) * 64 + dd) * 2048 + sS)) = hv;
            }
        }
        return;
    }

    f16* Ch = (f16*)(g_buf + cOff);
    const long cBase = (long)ch * chunkStride;
#pragma unroll
    for (int m = 0; m < 4; ++m) {
#pragma unroll
        for (int n = 0; n < 4; ++n) {
            const int c = col0 + wc + n * 16 + cB;
            const float bv = bp[c & 1023];
#pragma unroll
            for (int jj = 0; jj < 4; ++jj) {
                const int r = row0 + wr + m * 16 + hi * 4 + jj;
                float v = acc[m][n][jj] + bv;
                Ch[cBase + (long)r * ldc + (c & 1023)] = (f16)v;
            }
        }
    }
}

// ---------------------------------------------------------------------------
// GEMM v8 (r13 4-phase form): 256x256 tile, BK=64, 8 waves, counted vmcnt(4)
// at P1/P3 entry. All outputs f16. Split-K: bz=1 -> f16 partial to partOff,
// no bias.
// ---------------------------------------------------------------------------
template<int MODE>
__global__ __launch_bounds__(512, 1) void gemm8_k(
    long aOff, long bOff, long cOff, long partOff, long vtOff,
    const float* __restrict__ b0, const float* __restrict__ b1,
    const float* __restrict__ b2, const float* __restrict__ b3,
    int K, int lda, int ldb, int ldc, long chunkStride, int tvch)
{
    __shared__ alignas(16) f16 As[2][2][8192];   // [buf][khalf][256*32]
    __shared__ alignas(16) f16 Bs[2][2][8192];

    const int tid  = threadIdx.x;
    const int lane = tid & 63;
    const int w    = tid >> 6;
    const int cB   = lane & 15;
    const int hi   = lane >> 4;

    const int gx = gridDim.x, gy = gridDim.y;
    const int nwg = gx * gy * gridDim.z;
    const int id  = ((int)blockIdx.z * gy + (int)blockIdx.y) * gx + (int)blockIdx.x;
    const int swz = (id & 7) * (nwg >> 3) + (id >> 3);
    const int bx  = swz % gx;
    const int rem = swz / gx;
    const int by  = rem % gy;
    const int bz  = rem / gy;
    const int row0 = by * 256, col0 = bx * 256;

    const f16* Ab = (const f16*)(g_buf + aOff) + (long)bz * K;
    const f16* Bb = (const f16*)(g_buf + bOff) + (long)bz * K;

    const int wr = (w >> 2) * 128;
    const int wc = (w & 3) * 64;

    f32x4 acc[8][4] = {};

    auto stagePlane = [&](int buf, int kt, int mat, int kh) {
        const int kB = kt * 64 + kh * 32;
        const f16* src = mat ? Bb : Ab;
        const int ld   = mat ? ldb : lda;
        const int r0g  = mat ? col0 : row0;
        f16* dst = mat ? &Bs[buf][kh][0] : &As[buf][kh][0];
#pragma unroll
        for (int r = 0; r < 2; ++r) {
            const int idx  = r * 512 + w * 64 + lane;
            const int srow = idx >> 2, sb = idx & 3;
            const int gk = (sb ^ ((srow >> 1) & 3)) << 3;
            __builtin_amdgcn_global_load_lds(
                (const AS1 void*)(src + (long)(r0g + srow) * ld + kB + gk),
                (AS3 void*)(dst + (r * 512 + w * 64) * 8), 16, 0, 0);
        }
    };

    auto rdA = [&](int buf, int kh, int mf) -> f16x8 {
        const int row = wr + mf * 16 + cB;
        return *(const f16x8*)&As[buf][kh][row * 32 + ((hi ^ ((row >> 1) & 3)) << 3)];
    };
    auto rdB = [&](int buf, int kh, int nf) -> f16x8 {
        const int row = wc + nf * 16 + cB;
        return *(const f16x8*)&Bs[buf][kh][row * 32 + ((hi ^ ((row >> 1) & 3)) << 3)];
    };

    const int nt = K >> 6;
    stagePlane(0, 0, 0, 0);
    stagePlane(0, 0, 1, 0);
    stagePlane(0, 0, 0, 1);
    stagePlane(0, 0, 1, 1);

    for (int t = 0; t < nt; ++t) {
        const int cur = t & 1, nxt = cur ^ 1;
        const bool pf = (t + 1 < nt);
        f16x8 a[4], b[4];

        // ---- P1 ----
        asm volatile("s_waitcnt vmcnt(4)" ::: "memory");
        __builtin_amdgcn_s_barrier();
        __builtin_amdgcn_sched_barrier(0);
#pragma unroll
        for (int n = 0; n < 4; ++n) b[n] = rdB(cur, 0, n);
#pragma unroll
        for (int m = 0; m < 4; ++m) a[m] = rdA(cur, 0, m);
        if (pf) stagePlane(nxt, t + 1, 0, 0);
        asm volatile("s_waitcnt lgkmcnt(0)" ::: "memory");
        __builtin_amdgcn_sched_barrier(0);
        __builtin_amdgcn_s_setprio(1);
#pragma unroll
        for (int m = 0; m < 4; ++m)
#pragma unroll
            for (int n = 0; n < 4; ++n)
                acc[m][n] = __builtin_amdgcn_mfma_f32_16x16x32_f16(a[m], b[n], acc[m][n], 0, 0, 0);
        __builtin_amdgcn_s_setprio(0);

        // ---- P2 ----
        __builtin_amdgcn_s_barrier();
        __builtin_amdgcn_sched_barrier(0);
#pragma unroll
        for (int m = 0; m < 4; ++m) a[m] = rdA(cur, 0, m + 4);
        if (pf) stagePlane(nxt, t + 1, 1, 0);
        asm volatile("s_waitcnt lgkmcnt(0)" ::: "memory");
        __builtin_amdgcn_sched_barrier(0);
        __builtin_amdgcn_s_setprio(1);
#pragma unroll
        for (int m = 0; m < 4; ++m)
#pragma unroll
            for (int n = 0; n < 4; ++n)
                acc[4 + m][n] = __builtin_amdgcn_mfma_f32_16x16x32_f16(a[m], b[n], acc[4 + m][n], 0, 0, 0);
        __builtin_amdgcn_s_setprio(0);

        // ---- P3 ----
        if (pf) asm volatile("s_waitcnt vmcnt(4)" ::: "memory");
        else    asm volatile("s_waitcnt vmcnt(0)" ::: "memory");
        __builtin_amdgcn_s_barrier();
        __builtin_amdgcn_sched_barrier(0);
#pragma unroll
        for (int n = 0; n < 4; ++n) b[n] = rdB(cur, 1, n);
#pragma unroll
        for (int m = 0; m < 4; ++m) a[m] = rdA(cur, 1, m);
        if (pf) stagePlane(nxt, t + 1, 0, 1);
        asm volatile("s_waitcnt lgkmcnt(0)" ::: "memory");
        __builtin_amdgcn_sched_barrier(0);
        __builtin_amdgcn_s_setprio(1);
#pragma unroll
        for (int m = 0; m < 4; ++m)
#pragma unroll
            for (int n = 0; n < 4; ++n)
                acc[m][n] = __builtin_amdgcn_mfma_f32_16x16x32_f16(a[m], b[n], acc[m][n], 0, 0, 0);
        __builtin_amdgcn_s_setprio(0);

        // ---- P4 ----
        __builtin_amdgcn_s_barrier();
        __builtin_amdgcn_sched_barrier(0);
#pragma unroll
        for (int m = 0; m < 4; ++m) a[m] = rdA(cur, 1, m + 4);
        if (pf) stagePlane(nxt, t + 1, 1, 1);
        asm volatile("s_waitcnt lgkmcnt(0)" ::: "memory");
        __builtin_amdgcn_sched_barrier(0);
        __builtin_amdgcn_s_setprio(1);
#pragma unroll
        for (int m = 0; m < 4; ++m)
#pragma unroll
            for (int n = 0; n < 4; ++n)
                acc[4 + m][n] = __builtin_amdgcn_mfma_f32_16x16x32_f16(a[m], b[n], acc[4 + m][n], 0, 0, 0);
        __builtin_amdgcn_s_setprio(0);
    }

    const int ch = col0 >> 10;
    const float* bp = (ch == 0) ? b0 : (ch == 1) ? b1 : (ch == 2) ? b2 : b3;

    if (MODE == 0 && ch == tvch) {
        f16* Vt = (f16*)(g_buf + vtOff);
#pragma unroll
        for (int m = 0; m < 8; ++m) {
#pragma unroll
            for (int n = 0; n < 4; ++n) {
                const int c = col0 + wc + n * 16 + cB;
                const int hh = (c >> 6) & 15, dd = c & 63;
                const float bv = bp[c & 1023];
                const int r0e = row0 + wr + m * 16 + hi * 4;
                const int bb = r0e >> 11, sS = r0e & 2047;
                f16x4 hv;
#pragma unroll
                for (int jj = 0; jj < 4; ++jj) hv[jj] = (f16)(acc[m][n][jj] + bv);
                *(f16x4*)(Vt + (((long)(bb * 16 + hh) * 64 + dd) * 2048 + sS)) = hv;
            }
        }
        return;
    }

    f16* Ch = (f16*)(g_buf + (bz ? partOff : cOff));
    const long cBase = (long)ch * chunkStride;
#pragma unroll
    for (int m = 0; m < 8; ++m) {
#pragma unroll
        for (int n = 0; n < 4; ++n) {
            const int c = col0 + wc + n * 16 + cB;
            const float bv = bz ? 0.f : bp[c & 1023];
#pragma unroll
            for (int jj = 0; jj < 4; ++jj) {
                const int r = row0 + wr + m * 16 + hi * 4 + jj;
                float v = acc[m][n][jj] + bv;
                if constexpr (MODE == 1) v = fmaxf(v, 0.f);
                Ch[cBase + (long)r * ldc + (c & 1023)] = (f16)v;
            }
        }
    }
}

// ---------------------------------------------------------------------------
// Fused flash attention v8 (unchanged from r17): 128 kv per barrier, two
// 64-kv sub-iterations; K LDS [128][64], V LDS [64][128]; LDS 64KB.
// ---------------------------------------------------------------------------
template<int CAUSAL>
__global__ __launch_bounds__(512, 2) void flash_k(long qOff, long kOff, long vtOff, long oOff)
{
    __shared__ alignas(16) f16 SH[32768];   // [buf 16384 f16: K 8192 | V 8192]

    const int tid  = threadIdx.x;
    const int lane = tid & 63;
    const int w    = tid >> 6;
    const int ql   = lane & 31;
    const int s    = lane >> 5;

    const int raw   = (int)blockIdx.y * (int)gridDim.x + (int)blockIdx.x;  // 512
    const int newid = (raw & 7) * 64 + (raw >> 3);
    const int bh    = newid >> 3;
    const int p     = newid & 7;

    const int qt  = CAUSAL ? ((w >> 2) ? 15 - p : p) : (2 * p + (w >> 2));
    const int q0w = qt * 128 + (w & 3) * 32;
    const int nch = CAUSAL ? (16 - p) : 16;     // chunks of 128 kv

    const int b = bh >> 4, h = bh & 15;
    const long tokB = (long)b * S_LEN;

    const f16* Qb  = (const f16*)(g_buf + qOff);
    const f16* Kb  = (const f16*)(g_buf + kOff);
    const f16* Vtb = (const f16*)(g_buf + vtOff) + (long)bh * 64 * S_LEN;
    f16* Ob = (f16*)(g_buf + oOff);

    const int r8  = lane >> 3;
    const int c8  = lane & 7;
    const int sbK = c8 ^ r8;
    const int d16 = lane >> 4;
    const int b16 = lane & 15;

    auto stage = [&](int buf, int c) {
        const int kv0s = c * 128;
#pragma unroll
        for (int r = 0; r < 2; ++r) {
            const int row = w * 16 + r * 8 + r8;
            __builtin_amdgcn_global_load_lds(
                (const AS1 void*)(Kb + (tokB + kv0s + row) * DM + h * 64 + sbK * 8),
                (AS3 void*)(&SH[buf * 16384 + (w * 16 + r * 8) * 64]), 16, 0, 0);
        }
#pragma unroll
        for (int r = 0; r < 2; ++r) {
            const int d = w * 8 + r * 4 + d16;
            __builtin_amdgcn_global_load_lds(
                (const AS1 void*)(Vtb + (long)d * S_LEN + kv0s + (b16 ^ (d & 7)) * 8),
                (AS3 void*)(&SH[buf * 16384 + 8192 + (w * 8 + r * 4) * 128]), 16, 0, 0);
        }
    };

    stage(0, 0);

    f16x8 qf[4];
    {
        const f16 hs = (f16)(0.125f * 1.44269504088896f);
        const f16* qrow = Qb + (tokB + q0w + ql) * DM + h * 64 + s * 8;
#pragma unroll
        for (int kk = 0; kk < 4; ++kk) {
            qf[kk] = *(const f16x8*)(qrow + kk * 16);
#pragma unroll
            for (int i = 0; i < 8; ++i) qf[kk][i] = qf[kk][i] * hs;
        }
    }

    f32x16 oacc[2] = {};
    float lrow = 0.f;

    for (int c = 0; c < nch; ++c) {
        const int cur = c & 1;

        asm volatile("s_waitcnt vmcnt(0) lgkmcnt(0)" ::: "memory");
        __builtin_amdgcn_sched_barrier(0);
        __builtin_amdgcn_s_barrier();
        __builtin_amdgcn_sched_barrier(0);
        if (c + 1 < nch) stage(cur ^ 1, c + 1);

        const char* Kl = (const char*)SH + cur * 32768;
        const char* Vl = Kl + 16384;

#pragma unroll
        for (int sub = 0; sub < 2; ++sub) {
            const int kv0 = c * 128 + sub * 64;
            const bool active = !CAUSAL || (kv0 <= q0w + 31);
            if (!active) continue;

            f32x16 pr[2] = {};
            __builtin_amdgcn_s_setprio(1);
#pragma unroll
            for (int kk = 0; kk < 4; ++kk) {
                const int t16 = (kk * 2 + s) ^ (ql & 7);
                f16x8 kf0 = *(const f16x8*)(Kl + (sub * 64 + ql) * 128 + t16 * 16);
                f16x8 kf1 = *(const f16x8*)(Kl + (sub * 64 + 32 + ql) * 128 + t16 * 16);
                pr[0] = __builtin_amdgcn_mfma_f32_32x32x16_f16(kf0, qf[kk], pr[0], 0, 0, 0);
                pr[1] = __builtin_amdgcn_mfma_f32_32x32x16_f16(kf1, qf[kk], pr[1], 0, 0, 0);
            }
            __builtin_amdgcn_s_setprio(0);

            if (CAUSAL && (kv0 + 63 > q0w)) {
                const int q = q0w + ql;
#pragma unroll
                for (int v = 0; v < 2; ++v)
#pragma unroll
                    for (int r = 0; r < 16; ++r) {
                        const int kv = kv0 + v * 32 + (r & 3) + 8 * (r >> 2) + 4 * s;
                        if (kv > q) pr[v][r] = -1e30f;
                    }
            }

            u32 pk[2][4][2];
            float rp[4] = {0.f, 0.f, 0.f, 0.f};
#pragma unroll
            for (int v = 0; v < 2; ++v)
#pragma unroll
                for (int a = 0; a < 4; ++a)
#pragma unroll
                    for (int cc = 0; cc < 2; ++cc) {
                        const float e0 = __builtin_amdgcn_exp2f(pr[v][4 * a + 2 * cc] - 8.0f);
                        const float e1 = __builtin_amdgcn_exp2f(pr[v][4 * a + 2 * cc + 1] - 8.0f);
                        rp[a] += e0 + e1;
                        union { fp16x2 h; u32 u; } cv;
                        cv.h = __builtin_amdgcn_cvt_pkrtz(e0, e1);
                        pk[v][a][cc] = cv.u;
                    }
            float rsum = (rp[0] + rp[1]) + (rp[2] + rp[3]);
            rsum += __shfl_xor(rsum, 32);
            lrow += rsum;

            u32 loc[2][2][2], exv[2][2][2];
#pragma unroll
            for (int v = 0; v < 2; ++v)
#pragma unroll
                for (int k1 = 0; k1 < 2; ++k1)
#pragma unroll
                    for (int cc = 0; cc < 2; ++cc) {
                        const u32 pe = pk[v][2 * k1][cc];
                        const u32 po = pk[v][2 * k1 + 1][cc];
                        loc[v][k1][cc] = s ? po : pe;
                        const u32 snd = s ? pe : po;
                        exv[v][k1][cc] = (u32)__shfl_xor((int)snd, 32);
                    }

            __builtin_amdgcn_s_setprio(1);
#pragma unroll
            for (int ks = 0; ks < 4; ++ks) {
                const int v = ks >> 1, k1 = ks & 1;
                union { u32 u[4]; f16x8 hv; } pa;
                pa.u[0] = s ? exv[v][k1][0] : loc[v][k1][0];
                pa.u[1] = s ? exv[v][k1][1] : loc[v][k1][1];
                pa.u[2] = s ? loc[v][k1][0] : exv[v][k1][0];
                pa.u[3] = s ? loc[v][k1][1] : exv[v][k1][1];
                const int tv = sub * 8 + ((ks * 2 + s) ^ (ql & 7));
                f16x8 vf0 = *(const f16x8*)(Vl + ql * 256 + tv * 16);
                f16x8 vf1 = *(const f16x8*)(Vl + (32 + ql) * 256 + tv * 16);
                oacc[0] = __builtin_amdgcn_mfma_f32_32x32x16_f16(pa.hv, vf0, oacc[0], 0, 0, 0);
                oacc[1] = __builtin_amdgcn_mfma_f32_32x32x16_f16(pa.hv, vf1, oacc[1], 0, 0, 0);
            }
            __builtin_amdgcn_s_setprio(0);
        }
    }

    asm volatile("s_waitcnt lgkmcnt(0)" ::: "memory");
    __builtin_amdgcn_sched_barrier(0);
    __builtin_amdgcn_s_barrier();

    f16* Es = SH + w * 2304;
    const float linv = 1.0f / lrow;
#pragma unroll
    for (int r = 0; r < 16; ++r) {
        const int qr = (r & 3) + 8 * (r >> 2) + 4 * s;
        const float lb = __shfl(linv, qr);
        Es[qr * 72 + ql]      = (f16)(oacc[0][r] * lb);
        Es[qr * 72 + 32 + ql] = (f16)(oacc[1][r] * lb);
    }
    const int orow = lane >> 1;
    const int oh   = (lane & 1) * 32;
    const f16* srcp = Es + orow * 72 + oh;
    f16* dst = Ob + (tokB + q0w + orow) * DM + h * 64 + oh;
#pragma unroll
    for (int t = 0; t < 4; ++t)
        *(f16x8*)(dst + t * 8) = *(const f16x8*)(srcp + t * 8);
}

// ---------------------------------------------------------------------------
// fused residual-add + LayerNorm. Main input and optional in2 are f16 in
// g_buf; resid is external f32 OR f16 in g_buf (may alias outH).
// ---------------------------------------------------------------------------
__global__ __launch_bounds__(256) void ln_k(
    long inOff, long in2Off, const float* __restrict__ residF, long residHOff,
    const float* __restrict__ gamma, const float* __restrict__ beta,
    float* __restrict__ outFExt, long outHOff)
{
    const f16* in = (const f16*)(g_buf + inOff);

    const long row = blockIdx.x;
    const int tid = threadIdx.x;
    const int lane = tid & 63, wid = tid >> 6;

    f16x4 av = *(const f16x4*)(in + row * DM + tid * 4);
    float x0 = (float)av[0], x1 = (float)av[1], x2 = (float)av[2], x3 = (float)av[3];
    if (residF) {
        float4 rr = ((const float4*)(residF + row * DM))[tid];
        x0 += rr.x; x1 += rr.y; x2 += rr.z; x3 += rr.w;
    }
    if (residHOff >= 0) {
        const f16* rh = (const f16*)(g_buf + residHOff) + row * DM + tid * 4;
        f16x4 rv = *(const f16x4*)rh;
        x0 += (float)rv[0]; x1 += (float)rv[1]; x2 += (float)rv[2]; x3 += (float)rv[3];
    }
    if (in2Off >= 0) {
        const f16* in2 = (const f16*)(g_buf + in2Off) + row * DM + tid * 4;
        f16x4 pv = *(const f16x4*)in2;
        x0 += (float)pv[0]; x1 += (float)pv[1]; x2 += (float)pv[2]; x3 += (float)pv[3];
    }

    __shared__ float red[4];
    float ss = x0 + x1 + x2 + x3;
#pragma unroll
    for (int o = 32; o > 0; o >>= 1) ss += __shfl_xor(ss, o);
    if (lane == 0) red[wid] = ss;
    __syncthreads();
    const float mu = (red[0] + red[1] + red[2] + red[3]) * (1.0f / DM);

    float d0 = x0 - mu, d1 = x1 - mu, d2 = x2 - mu, d3 = x3 - mu;
    float qq = d0*d0 + d1*d1 + d2*d2 + d3*d3;
#pragma unroll
    for (int o = 32; o > 0; o >>= 1) qq += __shfl_xor(qq, o);
    __syncthreads();
    if (lane == 0) red[wid] = qq;
    __syncthreads();
    const float var = (red[0] + red[1] + red[2] + red[3]) * (1.0f / DM);
    const float rs = rsqrtf(var + 1e-6f);

    float4 g  = ((const float4*)gamma)[tid];
    float4 be = ((const float4*)beta)[tid];
    float y0 = d0 * rs * g.x + be.x;
    float y1 = d1 * rs * g.y + be.y;
    float y2 = d2 * rs * g.z + be.z;
    float y3 = d3 * rs * g.w + be.w;

    if (outFExt)
        ((float4*)(outFExt + row * DM))[tid] = make_float4(y0, y1, y2, y3);
    if (outHOff >= 0) {
        f16* outH = (f16*)(g_buf + outHOff);
        f16x4 hh; hh[0] = (f16)y0; hh[1] = (f16)y1; hh[2] = (f16)y2; hh[3] = (f16)y3;
        *(f16x4*)(outH + row * DM + tid * 4) = hh;
    }
}

// ---------------------------------------------------------------------------
extern "C" void kernel_launch(void* const* d_in, const int* in_sizes, int n_in,
                              void* d_out, int out_size, void* d_ws, size_t ws_size,
                              hipStream_t stream)
{
    (void)in_sizes; (void)n_in; (void)d_ws; (void)ws_size; (void)out_size;
    const float* x   = (const float*)d_in[0];
    const float* enc = (const float*)d_in[1];
    const float* wq1 = (const float*)d_in[2];  const float* bq1 = (const float*)d_in[3];
    const float* wk1 = (const float*)d_in[4];  const float* bk1 = (const float*)d_in[5];
    const float* wv1 = (const float*)d_in[6];  const float* bv1 = (const float*)d_in[7];
    const float* wo1 = (const float*)d_in[8];  const float* bo1 = (const float*)d_in[9];
    const float* wq2 = (const float*)d_in[10]; const float* bq2 = (const float*)d_in[11];
    const float* wk2 = (const float*)d_in[12]; const float* bk2 = (const float*)d_in[13];
    const float* wv2 = (const float*)d_in[14]; const float* bv2 = (const float*)d_in[15];
    const float* wo2 = (const float*)d_in[16]; const float* bo2 = (const float*)d_in[17];
    const float* wf1 = (const float*)d_in[18]; const float* bf1 = (const float*)d_in[19];
    const float* wf2 = (const float*)d_in[20]; const float* bf2 = (const float*)d_in[21];
    const float* g1  = (const float*)d_in[22]; const float* be1 = (const float*)d_in[23];
    const float* g2  = (const float*)d_in[24]; const float* be2 = (const float*)d_in[25];
    const float* g3  = (const float*)d_in[26]; const float* be3 = (const float*)d_in[27];
    float* out = (float*)d_out;

    const dim3 T256(256), T512(512), T32x8(32, 8);
    const long QKV_CHUNK = 8192L * 1024;

    // ---- converts + weight transposes ----
    cvt2_k<<<16384, T256, 0, stream>>>(x, enc);
    TWJobs jobs;
    jobs.src[0] = wq1; jobs.src[1] = wk1; jobs.src[2] = wv1; jobs.src[3] = wo1;
    jobs.src[4] = wq2; jobs.src[5] = wk2; jobs.src[6] = wv2; jobs.src[7] = wo2;
    jobs.src[8] = wf1; jobs.src[9] = wf2;
    transw_all_k<<<16384, T32x8, 0, stream>>>(jobs);

    // ---- masked self-attention ----
    gemm8_k<0><<<dim3(12, 32, 1), T512, 0, stream>>>(OFF_XB, WQ1T, OFF_Q, 0, OFF_VT,
        bq1, bk1, bv1, bv1, 1024, 1024, 1024, 1024, QKV_CHUNK, 2);
    flash_k<1><<<dim3(8, 64), T512, 0, stream>>>(OFF_Q, OFF_K, OFF_VT, OFF_AC);
    gemm3_k<0><<<dim3(8, 64), T256, 0, stream>>>(OFF_AC, WO1T, OFF_F2, 0,
        bo1, bo1, bo1, bo1, 1024, 1024, 1024, 1024, 1024, -1);
    // LN1: in = F2 f16; resid = x (ext f32); out -> XB f16
    ln_k<<<8192, T256, 0, stream>>>(OFF_F2, -1, x, -1, g1, be1, nullptr, OFF_XB);

    // ---- cross-attention (q=enc, k=enc, v=x1) ----
    gemm8_k<0><<<dim3(8, 32, 1), T512, 0, stream>>>(OFF_ENC, WQ2T, OFF_Q, 0, 0,
        bq2, bk2, bk2, bk2, 1024, 1024, 1024, 1024, QKV_CHUNK, -1);
    gemm3_k<0><<<dim3(8, 64), T256, 0, stream>>>(OFF_XB, WV2T, OFF_V, OFF_VT,
        bv2, bv2, bv2, bv2, 1024, 1024, 1024, 1024, 1024, 0);
    flash_k<0><<<dim3(8, 64), T512, 0, stream>>>(OFF_Q, OFF_K, OFF_VT, OFF_AC);
    gemm3_k<0><<<dim3(8, 64), T256, 0, stream>>>(OFF_AC, WO2T, OFF_F2, 0,
        bo2, bo2, bo2, bo2, 1024, 1024, 1024, 1024, 1024, -1);
    // LN2: in = F2 f16; resid = XB f16 (LN1 out); out -> XB f16
    ln_k<<<8192, T256, 0, stream>>>(OFF_F2, -1, nullptr, OFF_XB, g2, be2, nullptr, OFF_XB);

    // ---- feed-forward ----
    gemm8_k<1><<<dim3(16, 32, 1), T512, 0, stream>>>(OFF_XB, WF1T, OFF_HID, 0, 0,
        bf1, bf1 + 1024, bf1 + 2048, bf1 + 3072, 1024, 1024, 1024, 4096, 1024, -1);
    gemm8_k<0><<<dim3(4, 32, 2), T512, 0, stream>>>(OFF_HID, WF2T, OFF_F2, OFF_PART, 0,
        bf2, bf2, bf2, bf2, 2048, 4096, 4096, 1024, 1024, -1);
    // LN3: in = F2 f16 + in2 = PART f16; resid = XB f16; out -> external f32
    ln_k<<<8192, T256, 0, stream>>>(OFF_F2, OFF_PART, nullptr, OFF_XB, g3, be3, out, -1);
}

// Round 20
// 557.141 us; speedup vs baseline: 1.1051x; 1.0221x over previous
//
#include <hip/hip_runtime.h>

// ---------------------------------------------------------------------------
// Decoder layer (B=4, S=2048, D=1024, H=16, Dh=64, FF=4096), f32 in/out.
// Round 20: ONE change vs r19 — causal flash block remap for per-CU load
// balance: blocks raw and raw+256 (which the dispatcher co-locates on a CU)
// get the SAME (b,h) and p / 7-p -> every CU does exactly 25 chunks (was
// 25 avg / 31 worst). Cross mapping unchanged. All else = r19 (best, 569us).
// ---------------------------------------------------------------------------

typedef _Float16 f16;
typedef _Float16 f16x8 __attribute__((ext_vector_type(8)));
typedef _Float16 f16x4 __attribute__((ext_vector_type(4)));
typedef __fp16 fp16x2 __attribute__((ext_vector_type(2)));
typedef float f32x4 __attribute__((ext_vector_type(4)));
typedef float f32x16 __attribute__((ext_vector_type(16)));
typedef unsigned int u32;

#define AS1 __attribute__((address_space(1)))
#define AS3 __attribute__((address_space(3)))

constexpr int S_LEN = 2048;
constexpr int DM    = 1024;

// ---- static device arena (byte offsets) ----
constexpr long OFF_W    = 0;
constexpr long OFF_XB   = 32L  << 20;
constexpr long OFF_ENC  = 48L  << 20;
constexpr long OFF_Q    = 64L  << 20;
constexpr long OFF_K    = 80L  << 20;
constexpr long OFF_V    = 96L  << 20;
constexpr long OFF_VT   = 112L << 20;
constexpr long OFF_AC   = 128L << 20;
constexpr long OFF_HID  = 144L << 20;
constexpr long OFF_F2   = 240L << 20;      // f16
constexpr long OFF_PART = 304L << 20;      // f16 split-K partial
constexpr long BUF_BYTES = 336L << 20;

__device__ alignas(4096) unsigned char g_buf[BUF_BYTES];

constexpr long WQ1T = OFF_W + (0L  << 20);
constexpr long WF1T = OFF_W + (16L << 20);  // [4096][1024]
constexpr long WF2T = OFF_W + (24L << 20);  // [1024][4096]
constexpr long WO1T = OFF_W + (6L  << 20);
constexpr long WQ2T = OFF_W + (8L  << 20);
constexpr long WV2T = OFF_W + (12L << 20);
constexpr long WO2T = OFF_W + (14L << 20);

// ---------------------------------------------------------------------------
__global__ __launch_bounds__(256) void cvt2_k(const float* __restrict__ x,
                                              const float* __restrict__ enc)
{
    const int bid = blockIdx.x;
    const bool second = bid >= 8192;
    const float* in = second ? enc : x;
    f16* out = (f16*)(g_buf + (second ? OFF_ENC : OFF_XB));
    long i = (long)(second ? bid - 8192 : bid) * 256 + threadIdx.x;
    float4 v = ((const float4*)in)[i];
    f16x4 h;
    h[0] = (f16)v.x; h[1] = (f16)v.y; h[2] = (f16)v.z; h[3] = (f16)v.w;
    *(f16x4*)(out + i * 4) = h;
}

// ---------------------------------------------------------------------------
struct TWJobs { const float* src[10]; };

__global__ __launch_bounds__(256) void transw_all_k(TWJobs jobs)
{
    __shared__ float t[32][33];
    const int bid = blockIdx.x;
    int j, local;
    if (bid < 8192)       { j = bid >> 10; local = bid & 1023; }
    else if (bid < 12288) { j = 8; local = bid - 8192; }
    else                  { j = 9; local = bid - 12288; }
    const int K = (j == 9) ? 4096 : 1024;
    const int N = (j == 8) ? 4096 : 1024;
    const int tnx = N >> 5;
    const int tx32 = local % tnx, ty32 = local / tnx;
    const long dstOff = (j < 8) ? (long)j * (2L << 20) : ((j == 8) ? WF1T : WF2T);
    const float* W = jobs.src[j];
    f16* Wt = (f16*)(g_buf + dstOff);

    int tx = threadIdx.x, ty = threadIdx.y;
    int c0 = tx32 * 32, r0 = ty32 * 32;
#pragma unroll
    for (int i = 0; i < 4; ++i)
        t[ty + 8*i][tx] = W[(long)(r0 + ty + 8*i) * N + c0 + tx];
    __syncthreads();
#pragma unroll
    for (int i = 0; i < 4; ++i)
        Wt[(long)(c0 + ty + 8*i) * K + r0 + tx] = (f16)t[tx][ty + 8*i];
}

// ---------------------------------------------------------------------------
// GEMM v3: 128x128, BK=32, 4 waves, triple-buffered, counted vmcnt.
// Used for AO1/AO2 (MODE 0, f16 out) and V2 (MODE 0 + fused V-transpose).
// ---------------------------------------------------------------------------
template<int MODE>
__global__ __launch_bounds__(256) void gemm3_k(
    long aOff, long bOff, long cOff, long vtOff,
    const float* __restrict__ b0, const float* __restrict__ b1,
    const float* __restrict__ b2, const float* __restrict__ b3,
    int K, int lda, int ldb, int ldc, long chunkStride, int tvch)
{
    __shared__ alignas(16) f16 As[3][128 * 32];
    __shared__ alignas(16) f16 Bs[3][128 * 32];

    const int tid  = threadIdx.x;
    const int lane = tid & 63;
    const int w    = tid >> 6;
    const int cB   = lane & 15;
    const int hi   = lane >> 4;

    const int nwg = gridDim.x * gridDim.y;
    const int id  = blockIdx.y * gridDim.x + blockIdx.x;
    const int swz = (id & 7) * (nwg >> 3) + (id >> 3);
    const int bx  = swz % gridDim.x, by = swz / gridDim.x;
    const int row0 = by * 128, col0 = bx * 128;

    const f16* Ab = (const f16*)(g_buf + aOff);
    const f16* Bb = (const f16*)(g_buf + bOff);

    const int wr = (w >> 1) * 64;
    const int wc = (w & 1) * 64;

    f32x4 acc[4][4] = {};

    auto stage = [&](int buf, int kt) {
        const int kB = kt * 32;
        const int base = w * 64;
#pragma unroll
        for (int r = 0; r < 2; ++r) {
            const int idx  = r * 256 + base + lane;
            const int srow = idx >> 2, sb = idx & 3;
            const int gk = (sb ^ ((srow >> 1) & 3)) << 3;
            __builtin_amdgcn_global_load_lds(
                (const AS1 void*)(Ab + (long)(row0 + srow) * lda + kB + gk),
                (AS3 void*)(&As[buf][(r * 256 + base) * 8]), 16, 0, 0);
            __builtin_amdgcn_global_load_lds(
                (const AS1 void*)(Bb + (long)(col0 + srow) * ldb + kB + gk),
                (AS3 void*)(&Bs[buf][(r * 256 + base) * 8]), 16, 0, 0);
        }
    };

    const int nt = K >> 5;
    stage(0, 0);
    stage(1, 1);

    for (int t = 0; t < nt; ++t) {
        if (nt - t >= 2) asm volatile("s_waitcnt vmcnt(4)" ::: "memory");
        else             asm volatile("s_waitcnt vmcnt(0)" ::: "memory");
        __builtin_amdgcn_s_barrier();
        __builtin_amdgcn_sched_barrier(0);
        if (t + 2 < nt) stage((t + 2) % 3, t + 2);

        const int cur = t % 3;
        f16x8 af[4], bf[4];
#pragma unroll
        for (int m = 0; m < 4; ++m) {
            const int row = wr + m * 16 + cB;
            af[m] = *(const f16x8*)&As[cur][row * 32 + ((hi ^ ((row >> 1) & 3)) << 3)];
        }
#pragma unroll
        for (int n = 0; n < 4; ++n) {
            const int row = wc + n * 16 + cB;
            bf[n] = *(const f16x8*)&Bs[cur][row * 32 + ((hi ^ ((row >> 1) & 3)) << 3)];
        }
        __builtin_amdgcn_s_setprio(1);
#pragma unroll
        for (int m = 0; m < 4; ++m)
#pragma unroll
            for (int n = 0; n < 4; ++n)
                acc[m][n] = __builtin_amdgcn_mfma_f32_16x16x32_f16(af[m], bf[n], acc[m][n], 0, 0, 0);
        __builtin_amdgcn_s_setprio(0);
    }

    const int ch = col0 >> 10;
    const float* bp = (ch == 0) ? b0 : (ch == 1) ? b1 : (ch == 2) ? b2 : b3;

    if (MODE == 0 && ch == tvch) {
        f16* Vt = (f16*)(g_buf + vtOff);
#pragma unroll
        for (int m = 0; m < 4; ++m) {
#pragma unroll
            for (int n = 0; n < 4; ++n) {
                const int c = col0 + wc + n * 16 + cB;
                const int hh = (c >> 6) & 15, dd = c & 63;
                const float bv = bp[c & 1023];
                const int r0e = row0 + wr + m * 16 + hi * 4;
                const int bb = r0e >> 11, sS = r0e & 2047;
                f16x4 hv;
#pragma unroll
                for (int jj = 0; jj < 4; ++jj) hv[jj] = (f16)(acc[m][n][jj] + bv);
                *(f16x4*)(Vt + (((long)(bb * 16 + hh) * 64 + dd) * 2048 + sS)) = hv;
            }
        }
        return;
    }

    f16* Ch = (f16*)(g_buf + cOff);
    const long cBase = (long)ch * chunkStride;
#pragma unroll
    for (int m = 0; m < 4; ++m) {
#pragma unroll
        for (int n = 0; n < 4; ++n) {
            const int c = col0 + wc + n * 16 + cB;
            const float bv = bp[c & 1023];
#pragma unroll
            for (int jj = 0; jj < 4; ++jj) {
                const int r = row0 + wr + m * 16 + hi * 4 + jj;
                float v = acc[m][n][jj] + bv;
                Ch[cBase + (long)r * ldc + (c & 1023)] = (f16)v;
            }
        }
    }
}

// ---------------------------------------------------------------------------
// GEMM v8 (r13 4-phase form): 256x256 tile, BK=64, 8 waves, counted vmcnt(4)
// at P1/P3 entry. All outputs f16. Split-K: bz=1 -> f16 partial, no bias.
// ---------------------------------------------------------------------------
template<int MODE>
__global__ __launch_bounds__(512, 1) void gemm8_k(
    long aOff, long bOff, long cOff, long partOff, long vtOff,
    const float* __restrict__ b0, const float* __restrict__ b1,
    const float* __restrict__ b2, const float* __restrict__ b3,
    int K, int lda, int ldb, int ldc, long chunkStride, int tvch)
{
    __shared__ alignas(16) f16 As[2][2][8192];   // [buf][khalf][256*32]
    __shared__ alignas(16) f16 Bs[2][2][8192];

    const int tid  = threadIdx.x;
    const int lane = tid & 63;
    const int w    = tid >> 6;
    const int cB   = lane & 15;
    const int hi   = lane >> 4;

    const int gx = gridDim.x, gy = gridDim.y;
    const int nwg = gx * gy * gridDim.z;
    const int id  = ((int)blockIdx.z * gy + (int)blockIdx.y) * gx + (int)blockIdx.x;
    const int swz = (id & 7) * (nwg >> 3) + (id >> 3);
    const int bx  = swz % gx;
    const int rem = swz / gx;
    const int by  = rem % gy;
    const int bz  = rem / gy;
    const int row0 = by * 256, col0 = bx * 256;

    const f16* Ab = (const f16*)(g_buf + aOff) + (long)bz * K;
    const f16* Bb = (const f16*)(g_buf + bOff) + (long)bz * K;

    const int wr = (w >> 2) * 128;
    const int wc = (w & 3) * 64;

    f32x4 acc[8][4] = {};

    auto stagePlane = [&](int buf, int kt, int mat, int kh) {
        const int kB = kt * 64 + kh * 32;
        const f16* src = mat ? Bb : Ab;
        const int ld   = mat ? ldb : lda;
        const int r0g  = mat ? col0 : row0;
        f16* dst = mat ? &Bs[buf][kh][0] : &As[buf][kh][0];
#pragma unroll
        for (int r = 0; r < 2; ++r) {
            const int idx  = r * 512 + w * 64 + lane;
            const int srow = idx >> 2, sb = idx & 3;
            const int gk = (sb ^ ((srow >> 1) & 3)) << 3;
            __builtin_amdgcn_global_load_lds(
                (const AS1 void*)(src + (long)(r0g + srow) * ld + kB + gk),
                (AS3 void*)(dst + (r * 512 + w * 64) * 8), 16, 0, 0);
        }
    };

    auto rdA = [&](int buf, int kh, int mf) -> f16x8 {
        const int row = wr + mf * 16 + cB;
        return *(const f16x8*)&As[buf][kh][row * 32 + ((hi ^ ((row >> 1) & 3)) << 3)];
    };
    auto rdB = [&](int buf, int kh, int nf) -> f16x8 {
        const int row = wc + nf * 16 + cB;
        return *(const f16x8*)&Bs[buf][kh][row * 32 + ((hi ^ ((row >> 1) & 3)) << 3)];
    };

    const int nt = K >> 6;
    stagePlane(0, 0, 0, 0);
    stagePlane(0, 0, 1, 0);
    stagePlane(0, 0, 0, 1);
    stagePlane(0, 0, 1, 1);

    for (int t = 0; t < nt; ++t) {
        const int cur = t & 1, nxt = cur ^ 1;
        const bool pf = (t + 1 < nt);
        f16x8 a[4], b[4];

        // ---- P1 ----
        asm volatile("s_waitcnt vmcnt(4)" ::: "memory");
        __builtin_amdgcn_s_barrier();
        __builtin_amdgcn_sched_barrier(0);
#pragma unroll
        for (int n = 0; n < 4; ++n) b[n] = rdB(cur, 0, n);
#pragma unroll
        for (int m = 0; m < 4; ++m) a[m] = rdA(cur, 0, m);
        if (pf) stagePlane(nxt, t + 1, 0, 0);
        asm volatile("s_waitcnt lgkmcnt(0)" ::: "memory");
        __builtin_amdgcn_sched_barrier(0);
        __builtin_amdgcn_s_setprio(1);
#pragma unroll
        for (int m = 0; m < 4; ++m)
#pragma unroll
            for (int n = 0; n < 4; ++n)
                acc[m][n] = __builtin_amdgcn_mfma_f32_16x16x32_f16(a[m], b[n], acc[m][n], 0, 0, 0);
        __builtin_amdgcn_s_setprio(0);

        // ---- P2 ----
        __builtin_amdgcn_s_barrier();
        __builtin_amdgcn_sched_barrier(0);
#pragma unroll
        for (int m = 0; m < 4; ++m) a[m] = rdA(cur, 0, m + 4);
        if (pf) stagePlane(nxt, t + 1, 1, 0);
        asm volatile("s_waitcnt lgkmcnt(0)" ::: "memory");
        __builtin_amdgcn_sched_barrier(0);
        __builtin_amdgcn_s_setprio(1);
#pragma unroll
        for (int m = 0; m < 4; ++m)
#pragma unroll
            for (int n = 0; n < 4; ++n)
                acc[4 + m][n] = __builtin_amdgcn_mfma_f32_16x16x32_f16(a[m], b[n], acc[4 + m][n], 0, 0, 0);
        __builtin_amdgcn_s_setprio(0);

        // ---- P3 ----
        if (pf) asm volatile("s_waitcnt vmcnt(4)" ::: "memory");
        else    asm volatile("s_waitcnt vmcnt(0)" ::: "memory");
        __builtin_amdgcn_s_barrier();
        __builtin_amdgcn_sched_barrier(0);
#pragma unroll
        for (int n = 0; n < 4; ++n) b[n] = rdB(cur, 1, n);
#pragma unroll
        for (int m = 0; m < 4; ++m) a[m] = rdA(cur, 1, m);
        if (pf) stagePlane(nxt, t + 1, 0, 1);
        asm volatile("s_waitcnt lgkmcnt(0)" ::: "memory");
        __builtin_amdgcn_sched_barrier(0);
        __builtin_amdgcn_s_setprio(1);
#pragma unroll
        for (int m = 0; m < 4; ++m)
#pragma unroll
            for (int n = 0; n < 4; ++n)
                acc[m][n] = __builtin_amdgcn_mfma_f32_16x16x32_f16(a[m], b[n], acc[m][n], 0, 0, 0);
        __builtin_amdgcn_s_setprio(0);

        // ---- P4 ----
        __builtin_amdgcn_s_barrier();
        __builtin_amdgcn_sched_barrier(0);
#pragma unroll
        for (int m = 0; m < 4; ++m) a[m] = rdA(cur, 1, m + 4);
        if (pf) stagePlane(nxt, t + 1, 1, 1);
        asm volatile("s_waitcnt lgkmcnt(0)" ::: "memory");
        __builtin_amdgcn_sched_barrier(0);
        __builtin_amdgcn_s_setprio(1);
#pragma unroll
        for (int m = 0; m < 4; ++m)
#pragma unroll
            for (int n = 0; n < 4; ++n)
                acc[4 + m][n] = __builtin_amdgcn_mfma_f32_16x16x32_f16(a[m], b[n], acc[4 + m][n], 0, 0, 0);
        __builtin_amdgcn_s_setprio(0);
    }

    const int ch = col0 >> 10;
    const float* bp = (ch == 0) ? b0 : (ch == 1) ? b1 : (ch == 2) ? b2 : b3;

    if (MODE == 0 && ch == tvch) {
        f16* Vt = (f16*)(g_buf + vtOff);
#pragma unroll
        for (int m = 0; m < 8; ++m) {
#pragma unroll
            for (int n = 0; n < 4; ++n) {
                const int c = col0 + wc + n * 16 + cB;
                const int hh = (c >> 6) & 15, dd = c & 63;
                const float bv = bp[c & 1023];
                const int r0e = row0 + wr + m * 16 + hi * 4;
                const int bb = r0e >> 11, sS = r0e & 2047;
                f16x4 hv;
#pragma unroll
                for (int jj = 0; jj < 4; ++jj) hv[jj] = (f16)(acc[m][n][jj] + bv);
                *(f16x4*)(Vt + (((long)(bb * 16 + hh) * 64 + dd) * 2048 + sS)) = hv;
            }
        }
        return;
    }

    f16* Ch = (f16*)(g_buf + (bz ? partOff : cOff));
    const long cBase = (long)ch * chunkStride;
#pragma unroll
    for (int m = 0; m < 8; ++m) {
#pragma unroll
        for (int n = 0; n < 4; ++n) {
            const int c = col0 + wc + n * 16 + cB;
            const float bv = bz ? 0.f : bp[c & 1023];
#pragma unroll
            for (int jj = 0; jj < 4; ++jj) {
                const int r = row0 + wr + m * 16 + hi * 4 + jj;
                float v = acc[m][n][jj] + bv;
                if constexpr (MODE == 1) v = fmaxf(v, 0.f);
                Ch[cBase + (long)r * ldc + (c & 1023)] = (f16)v;
            }
        }
    }
}

// ---------------------------------------------------------------------------
// Fused flash attention v8 + causal CU-pair balance:
// CAUSAL: blocks raw and raw+256 share a CU (dispatch model: XCD = raw%8,
// round-robin within XCD). Map raw<256 -> (bh=raw>>2, p=raw&3);
// raw>=256 -> (bh=(raw-256)>>2, p=7-((raw-256)&3)). Each CU: same (b,h),
// p + (7-p) -> constant 25 chunks. Cross mapping unchanged.
// ---------------------------------------------------------------------------
template<int CAUSAL>
__global__ __launch_bounds__(512, 2) void flash_k(long qOff, long kOff, long vtOff, long oOff)
{
    __shared__ alignas(16) f16 SH[32768];   // [buf 16384 f16: K 8192 | V 8192]

    const int tid  = threadIdx.x;
    const int lane = tid & 63;
    const int w    = tid >> 6;
    const int ql   = lane & 31;
    const int s    = lane >> 5;

    const int raw = (int)blockIdx.y * (int)gridDim.x + (int)blockIdx.x;  // 512
    int bh, p;
    if (CAUSAL) {
        const int half = raw >> 8;            // 0 | 1 (co-resident partner)
        const int k    = raw & 255;
        bh = k >> 2;
        const int ph = k & 3;
        p  = half ? (7 - ph) : ph;
    } else {
        const int newid = (raw & 7) * 64 + (raw >> 3);
        bh = newid >> 3;
        p  = newid & 7;
    }

    const int qt  = CAUSAL ? ((w >> 2) ? 15 - p : p) : (2 * p + (w >> 2));
    const int q0w = qt * 128 + (w & 3) * 32;
    const int nch = CAUSAL ? (16 - p) : 16;     // chunks of 128 kv

    const int b = bh >> 4, h = bh & 15;
    const long tokB = (long)b * S_LEN;

    const f16* Qb  = (const f16*)(g_buf + qOff);
    const f16* Kb  = (const f16*)(g_buf + kOff);
    const f16* Vtb = (const f16*)(g_buf + vtOff) + (long)bh * 64 * S_LEN;
    f16* Ob = (f16*)(g_buf + oOff);

    const int r8  = lane >> 3;
    const int c8  = lane & 7;
    const int sbK = c8 ^ r8;
    const int d16 = lane >> 4;
    const int b16 = lane & 15;

    auto stage = [&](int buf, int c) {
        const int kv0s = c * 128;
#pragma unroll
        for (int r = 0; r < 2; ++r) {
            const int row = w * 16 + r * 8 + r8;
            __builtin_amdgcn_global_load_lds(
                (const AS1 void*)(Kb + (tokB + kv0s + row) * DM + h * 64 + sbK * 8),
                (AS3 void*)(&SH[buf * 16384 + (w * 16 + r * 8) * 64]), 16, 0, 0);
        }
#pragma unroll
        for (int r = 0; r < 2; ++r) {
            const int d = w * 8 + r * 4 + d16;
            __builtin_amdgcn_global_load_lds(
                (const AS1 void*)(Vtb + (long)d * S_LEN + kv0s + (b16 ^ (d & 7)) * 8),
                (AS3 void*)(&SH[buf * 16384 + 8192 + (w * 8 + r * 4) * 128]), 16, 0, 0);
        }
    };

    stage(0, 0);

    f16x8 qf[4];
    {
        const f16 hs = (f16)(0.125f * 1.44269504088896f);
        const f16* qrow = Qb + (tokB + q0w + ql) * DM + h * 64 + s * 8;
#pragma unroll
        for (int kk = 0; kk < 4; ++kk) {
            qf[kk] = *(const f16x8*)(qrow + kk * 16);
#pragma unroll
            for (int i = 0; i < 8; ++i) qf[kk][i] = qf[kk][i] * hs;
        }
    }

    f32x16 oacc[2] = {};
    float lrow = 0.f;

    for (int c = 0; c < nch; ++c) {
        const int cur = c & 1;

        asm volatile("s_waitcnt vmcnt(0) lgkmcnt(0)" ::: "memory");
        __builtin_amdgcn_sched_barrier(0);
        __builtin_amdgcn_s_barrier();
        __builtin_amdgcn_sched_barrier(0);
        if (c + 1 < nch) stage(cur ^ 1, c + 1);

        const char* Kl = (const char*)SH + cur * 32768;
        const char* Vl = Kl + 16384;

#pragma unroll
        for (int sub = 0; sub < 2; ++sub) {
            const int kv0 = c * 128 + sub * 64;
            const bool active = !CAUSAL || (kv0 <= q0w + 31);
            if (!active) continue;

            f32x16 pr[2] = {};
            __builtin_amdgcn_s_setprio(1);
#pragma unroll
            for (int kk = 0; kk < 4; ++kk) {
                const int t16 = (kk * 2 + s) ^ (ql & 7);
                f16x8 kf0 = *(const f16x8*)(Kl + (sub * 64 + ql) * 128 + t16 * 16);
                f16x8 kf1 = *(const f16x8*)(Kl + (sub * 64 + 32 + ql) * 128 + t16 * 16);
                pr[0] = __builtin_amdgcn_mfma_f32_32x32x16_f16(kf0, qf[kk], pr[0], 0, 0, 0);
                pr[1] = __builtin_amdgcn_mfma_f32_32x32x16_f16(kf1, qf[kk], pr[1], 0, 0, 0);
            }
            __builtin_amdgcn_s_setprio(0);

            if (CAUSAL && (kv0 + 63 > q0w)) {
                const int q = q0w + ql;
#pragma unroll
                for (int v = 0; v < 2; ++v)
#pragma unroll
                    for (int r = 0; r < 16; ++r) {
                        const int kv = kv0 + v * 32 + (r & 3) + 8 * (r >> 2) + 4 * s;
                        if (kv > q) pr[v][r] = -1e30f;
                    }
            }

            u32 pk[2][4][2];
            float rp[4] = {0.f, 0.f, 0.f, 0.f};
#pragma unroll
            for (int v = 0; v < 2; ++v)
#pragma unroll
                for (int a = 0; a < 4; ++a)
#pragma unroll
                    for (int cc = 0; cc < 2; ++cc) {
                        const float e0 = __builtin_amdgcn_exp2f(pr[v][4 * a + 2 * cc] - 8.0f);
                        const float e1 = __builtin_amdgcn_exp2f(pr[v][4 * a + 2 * cc + 1] - 8.0f);
                        rp[a] += e0 + e1;
                        union { fp16x2 h; u32 u; } cv;
                        cv.h = __builtin_amdgcn_cvt_pkrtz(e0, e1);
                        pk[v][a][cc] = cv.u;
                    }
            float rsum = (rp[0] + rp[1]) + (rp[2] + rp[3]);
            rsum += __shfl_xor(rsum, 32);
            lrow += rsum;

            u32 loc[2][2][2], exv[2][2][2];
#pragma unroll
            for (int v = 0; v < 2; ++v)
#pragma unroll
                for (int k1 = 0; k1 < 2; ++k1)
#pragma unroll
                    for (int cc = 0; cc < 2; ++cc) {
                        const u32 pe = pk[v][2 * k1][cc];
                        const u32 po = pk[v][2 * k1 + 1][cc];
                        loc[v][k1][cc] = s ? po : pe;
                        const u32 snd = s ? pe : po;
                        exv[v][k1][cc] = (u32)__shfl_xor((int)snd, 32);
                    }

            __builtin_amdgcn_s_setprio(1);
#pragma unroll
            for (int ks = 0; ks < 4; ++ks) {
                const int v = ks >> 1, k1 = ks & 1;
                union { u32 u[4]; f16x8 hv; } pa;
                pa.u[0] = s ? exv[v][k1][0] : loc[v][k1][0];
                pa.u[1] = s ? exv[v][k1][1] : loc[v][k1][1];
                pa.u[2] = s ? loc[v][k1][0] : exv[v][k1][0];
                pa.u[3] = s ? loc[v][k1][1] : exv[v][k1][1];
                const int tv = sub * 8 + ((ks * 2 + s) ^ (ql & 7));
                f16x8 vf0 = *(const f16x8*)(Vl + ql * 256 + tv * 16);
                f16x8 vf1 = *(const f16x8*)(Vl + (32 + ql) * 256 + tv * 16);
                oacc[0] = __builtin_amdgcn_mfma_f32_32x32x16_f16(pa.hv, vf0, oacc[0], 0, 0, 0);
                oacc[1] = __builtin_amdgcn_mfma_f32_32x32x16_f16(pa.hv, vf1, oacc[1], 0, 0, 0);
            }
            __builtin_amdgcn_s_setprio(0);
        }
    }

    asm volatile("s_waitcnt lgkmcnt(0)" ::: "memory");
    __builtin_amdgcn_sched_barrier(0);
    __builtin_amdgcn_s_barrier();

    f16* Es = SH + w * 2304;
    const float linv = 1.0f / lrow;
#pragma unroll
    for (int r = 0; r < 16; ++r) {
        const int qr = (r & 3) + 8 * (r >> 2) + 4 * s;
        const float lb = __shfl(linv, qr);
        Es[qr * 72 + ql]      = (f16)(oacc[0][r] * lb);
        Es[qr * 72 + 32 + ql] = (f16)(oacc[1][r] * lb);
    }
    const int orow = lane >> 1;
    const int oh   = (lane & 1) * 32;
    const f16* srcp = Es + orow * 72 + oh;
    f16* dst = Ob + (tokB + q0w + orow) * DM + h * 64 + oh;
#pragma unroll
    for (int t = 0; t < 4; ++t)
        *(f16x8*)(dst + t * 8) = *(const f16x8*)(srcp + t * 8);
}

// ---------------------------------------------------------------------------
// fused residual-add + LayerNorm (r19 form: f16 main/in2 inputs).
// ---------------------------------------------------------------------------
__global__ __launch_bounds__(256) void ln_k(
    long inOff, long in2Off, const float* __restrict__ residF, long residHOff,
    const float* __restrict__ gamma, const float* __restrict__ beta,
    float* __restrict__ outFExt, long outHOff)
{
    const f16* in = (const f16*)(g_buf + inOff);

    const long row = blockIdx.x;
    const int tid = threadIdx.x;
    const int lane = tid & 63, wid = tid >> 6;

    f16x4 av = *(const f16x4*)(in + row * DM + tid * 4);
    float x0 = (float)av[0], x1 = (float)av[1], x2 = (float)av[2], x3 = (float)av[3];
    if (residF) {
        float4 rr = ((const float4*)(residF + row * DM))[tid];
        x0 += rr.x; x1 += rr.y; x2 += rr.z; x3 += rr.w;
    }
    if (residHOff >= 0) {
        const f16* rh = (const f16*)(g_buf + residHOff) + row * DM + tid * 4;
        f16x4 rv = *(const f16x4*)rh;
        x0 += (float)rv[0]; x1 += (float)rv[1]; x2 += (float)rv[2]; x3 += (float)rv[3];
    }
    if (in2Off >= 0) {
        const f16* in2 = (const f16*)(g_buf + in2Off) + row * DM + tid * 4;
        f16x4 pv = *(const f16x4*)in2;
        x0 += (float)pv[0]; x1 += (float)pv[1]; x2 += (float)pv[2]; x3 += (float)pv[3];
    }

    __shared__ float red[4];
    float ss = x0 + x1 + x2 + x3;
#pragma unroll
    for (int o = 32; o > 0; o >>= 1) ss += __shfl_xor(ss, o);
    if (lane == 0) red[wid] = ss;
    __syncthreads();
    const float mu = (red[0] + red[1] + red[2] + red[3]) * (1.0f / DM);

    float d0 = x0 - mu, d1 = x1 - mu, d2 = x2 - mu, d3 = x3 - mu;
    float qq = d0*d0 + d1*d1 + d2*d2 + d3*d3;
#pragma unroll
    for (int o = 32; o > 0; o >>= 1) qq += __shfl_xor(qq, o);
    __syncthreads();
    if (lane == 0) red[wid] = qq;
    __syncthreads();
    const float var = (red[0] + red[1] + red[2] + red[3]) * (1.0f / DM);
    const float rs = rsqrtf(var + 1e-6f);

    float4 g  = ((const float4*)gamma)[tid];
    float4 be = ((const float4*)beta)[tid];
    float y0 = d0 * rs * g.x + be.x;
    float y1 = d1 * rs * g.y + be.y;
    float y2 = d2 * rs * g.z + be.z;
    float y3 = d3 * rs * g.w + be.w;

    if (outFExt)
        ((float4*)(outFExt + row * DM))[tid] = make_float4(y0, y1, y2, y3);
    if (outHOff >= 0) {
        f16* outH = (f16*)(g_buf + outHOff);
        f16x4 hh; hh[0] = (f16)y0; hh[1] = (f16)y1; hh[2] = (f16)y2; hh[3] = (f16)y3;
        *(f16x4*)(outH + row * DM + tid * 4) = hh;
    }
}

// ---------------------------------------------------------------------------
extern "C" void kernel_launch(void* const* d_in, const int* in_sizes, int n_in,
                              void* d_out, int out_size, void* d_ws, size_t ws_size,
                              hipStream_t stream)
{
    (void)in_sizes; (void)n_in; (void)d_ws; (void)ws_size; (void)out_size;
    const float* x   = (const float*)d_in[0];
    const float* enc = (const float*)d_in[1];
    const float* wq1 = (const float*)d_in[2];  const float* bq1 = (const float*)d_in[3];
    const float* wk1 = (const float*)d_in[4];  const float* bk1 = (const float*)d_in[5];
    const float* wv1 = (const float*)d_in[6];  const float* bv1 = (const float*)d_in[7];
    const float* wo1 = (const float*)d_in[8];  const float* bo1 = (const float*)d_in[9];
    const float* wq2 = (const float*)d_in[10]; const float* bq2 = (const float*)d_in[11];
    const float* wk2 = (const float*)d_in[12]; const float* bk2 = (const float*)d_in[13];
    const float* wv2 = (const float*)d_in[14]; const float* bv2 = (const float*)d_in[15];
    const float* wo2 = (const float*)d_in[16]; const float* bo2 = (const float*)d_in[17];
    const float* wf1 = (const float*)d_in[18]; const float* bf1 = (const float*)d_in[19];
    const float* wf2 = (const float*)d_in[20]; const float* bf2 = (const float*)d_in[21];
    const float* g1  = (const float*)d_in[22]; const float* be1 = (const float*)d_in[23];
    const float* g2  = (const float*)d_in[24]; const float* be2 = (const float*)d_in[25];
    const float* g3  = (const float*)d_in[26]; const float* be3 = (const float*)d_in[27];
    float* out = (float*)d_out;

    const dim3 T256(256), T512(512), T32x8(32, 8);
    const long QKV_CHUNK = 8192L * 1024;

    // ---- converts + weight transposes ----
    cvt2_k<<<16384, T256, 0, stream>>>(x, enc);
    TWJobs jobs;
    jobs.src[0] = wq1; jobs.src[1] = wk1; jobs.src[2] = wv1; jobs.src[3] = wo1;
    jobs.src[4] = wq2; jobs.src[5] = wk2; jobs.src[6] = wv2; jobs.src[7] = wo2;
    jobs.src[8] = wf1; jobs.src[9] = wf2;
    transw_all_k<<<16384, T32x8, 0, stream>>>(jobs);

    // ---- masked self-attention ----
    gemm8_k<0><<<dim3(12, 32, 1), T512, 0, stream>>>(OFF_XB, WQ1T, OFF_Q, 0, OFF_VT,
        bq1, bk1, bv1, bv1, 1024, 1024, 1024, 1024, QKV_CHUNK, 2);
    flash_k<1><<<dim3(8, 64), T512, 0, stream>>>(OFF_Q, OFF_K, OFF_VT, OFF_AC);
    gemm3_k<0><<<dim3(8, 64), T256, 0, stream>>>(OFF_AC, WO1T, OFF_F2, 0,
        bo1, bo1, bo1, bo1, 1024, 1024, 1024, 1024, 1024, -1);
    // LN1: in = F2 f16; resid = x (ext f32); out -> XB f16
    ln_k<<<8192, T256, 0, stream>>>(OFF_F2, -1, x, -1, g1, be1, nullptr, OFF_XB);

    // ---- cross-attention (q=enc, k=enc, v=x1) ----
    gemm8_k<0><<<dim3(8, 32, 1), T512, 0, stream>>>(OFF_ENC, WQ2T, OFF_Q, 0, 0,
        bq2, bk2, bk2, bk2, 1024, 1024, 1024, 1024, QKV_CHUNK, -1);
    gemm3_k<0><<<dim3(8, 64), T256, 0, stream>>>(OFF_XB, WV2T, OFF_V, OFF_VT,
        bv2, bv2, bv2, bv2, 1024, 1024, 1024, 1024, 1024, 0);
    flash_k<0><<<dim3(8, 64), T512, 0, stream>>>(OFF_Q, OFF_K, OFF_VT, OFF_AC);
    gemm3_k<0><<<dim3(8, 64), T256, 0, stream>>>(OFF_AC, WO2T, OFF_F2, 0,
        bo2, bo2, bo2, bo2, 1024, 1024, 1024, 1024, 1024, -1);
    // LN2: in = F2 f16; resid = XB f16 (LN1 out); out -> XB f16
    ln_k<<<8192, T256, 0, stream>>>(OFF_F2, -1, nullptr, OFF_XB, g2, be2, nullptr, OFF_XB);

    // ---- feed-forward ----
    gemm8_k<1><<<dim3(16, 32, 1), T512, 0, stream>>>(OFF_XB, WF1T, OFF_HID, 0, 0,
        bf1, bf1 + 1024, bf1 + 2048, bf1 + 3072, 1024, 1024, 1024, 4096, 1024, -1);
    gemm8_k<0><<<dim3(4, 32, 2), T512, 0, stream>>>(OFF_HID, WF2T, OFF_F2, OFF_PART, 0,
        bf2, bf2, bf2, bf2, 2048, 4096, 4096, 1024, 1024, -1);
    // LN3: in = F2 f16 + in2 = PART f16; resid = XB f16; out -> external f32
    ln_k<<<8192, T256, 0, stream>>>(OFF_F2, OFF_PART, nullptr, OFF_XB, g3, be3, out, -1);
}